// Round 1
// baseline (2636.713 us; speedup 1.0000x reference)
//
#include <hip/hip_runtime.h>
#include <hip/hip_bf16.h>

// ---------------- problem constants ----------------
constexpr int Bc = 2, Nc = 256, CHM = 62;
constexpr int HW = 180;            // heatmap H=W
constexpr int OH = 38;             // conv out H=W
constexpr int Pp = OH * OH;        // 1444 positions
constexpr int NIMG = Bc * Nc;      // 512 images (n-major: img = n*B + b)
constexpr int RYB = 10;            // row-blocks per image (4 rows, last has 2)
constexpr int NBLK = NIMG * RYB;   // 5120 conv blocks

// ---------------- ws layout (bytes) ----------------
constexpr size_t OFF_THETA = 0;            // 512*6*4        = 12,288
constexpr size_t OFF_WB    = 16384;        // 62*3*64*4 bf16 = 95,232
constexpr size_t OFF_PART  = 131072;       // 5120*64*2*4    = 2,621,440
constexpr size_t OFF_AB    = 2752512;      // 64*2*4         = 512
constexpr size_t OFF_POOLP = OFF_PART;     // aliases partials (consumed before reuse)
constexpr size_t OFF_CONV  = 4194304;      // 512*1444*64*2  = 94,633,984
constexpr size_t WS_MIN        = OFF_AB + 512;
constexpr size_t WS_STORE_NEED = OFF_CONV + (size_t)NIMG * Pp * 64 * 2;

// ---------------- smem layout for k_conv (dynamic, 127,040 B) ----------------
constexpr int SM_STRIP = 0;        // bf16 strip [6][62][40]      = 29,760 B
constexpr int SM_W     = 29760;    // bf16 weights [62][3][64][4] = 95,232 B
constexpr int SM_RED   = 124992;   // float red [4][64][2]        =  2,048 B
constexpr int SM_TOTAL = 127040;

__device__ __forceinline__ float bflo(unsigned u) { return __uint_as_float(u << 16); }
__device__ __forceinline__ float bfhi(unsigned u) { return __uint_as_float(u & 0xffff0000u); }

// ============ K1: fc_loc MLP -> theta[img][6], img = n*B + b ============
__global__ void k_theta(const float* __restrict__ q,
                        const float* __restrict__ w1, const float* __restrict__ b1,
                        const float* __restrict__ w2, const float* __restrict__ b2,
                        const float* __restrict__ w3, const float* __restrict__ b3,
                        float* __restrict__ theta) {
    __shared__ float qv[256], h1[64], h2[64];
    int qi = blockIdx.x;           // = b*N + n
    int t  = threadIdx.x;          // 64 threads
    int b = qi >> 8, n = qi & 255;
    const float* qrow = q + qi * 256;
    for (int i = t; i < 256; i += 64) qv[i] = qrow[i];
    __syncthreads();
    float s = b1[t];
    const float* wr = w1 + t * 256;
    for (int i = 0; i < 256; ++i) s = fmaf(qv[i], wr[i], s);
    h1[t] = fmaxf(s, 0.f);
    __syncthreads();
    s = b2[t]; wr = w2 + t * 64;
    for (int i = 0; i < 64; ++i) s = fmaf(h1[i], wr[i], s);
    h2[t] = fmaxf(s, 0.f);
    __syncthreads();
    if (t < 6) {
        s = b3[t]; wr = w3 + t * 64;
        for (int i = 0; i < 64; ++i) s = fmaf(h2[i], wr[i], s);
        theta[(n * Bc + b) * 6 + t] = s;
    }
}

// ============ K2: conv1 weights fp32 [oc][ic][ky][kx] -> bf16 [ic][ky][oc][4] ============
__global__ void k_wcvt(const float* __restrict__ w, __hip_bfloat16* __restrict__ wb) {
    int idx = blockIdx.x * 256 + threadIdx.x;      // over (ic,ky,oc) triples
    if (idx < CHM * 3 * 64) {
        int ic = idx / 192, r = idx % 192, ky = r >> 6, oc = r & 63;
        const float* src = w + ((oc * CHM + ic) * 3 + ky) * 3;
        __hip_bfloat16* dst = wb + (size_t)idx * 4;
        dst[0] = __float2bfloat16(src[0]);
        dst[1] = __float2bfloat16(src[1]);
        dst[2] = __float2bfloat16(src[2]);
        dst[3] = __float2bfloat16(0.f);
    }
}

// ============ K3: fused sample + 3x3 conv ============
// MODE 0: conv -> write conv_out(bf16) + per-block channel sum/sumsq
// MODE 1: conv -> per-block channel sum/sumsq only
// MODE 2: conv -> BN+ReLU+partial spatial pool (needs ab)
template<int MODE>
__global__ __launch_bounds__(256) void k_conv(
    const float* __restrict__ heatmap, const float* __restrict__ theta,
    const unsigned* __restrict__ wb_g, const float* __restrict__ bias,
    const float* __restrict__ ab, float* __restrict__ partials,
    __hip_bfloat16* __restrict__ conv_out, float* __restrict__ poolp) {
    extern __shared__ char smem[];
    __hip_bfloat16* strip = (__hip_bfloat16*)(smem + SM_STRIP);   // [6][62][40]
    __hip_bfloat16* wlds  = (__hip_bfloat16*)(smem + SM_W);       // [62][3][64][4]
    float* red = (float*)(smem + SM_RED);                         // [4][64][2]

    int bid = blockIdx.x;
    int img = bid / RYB, ry = bid % RYB;
    int oy0 = ry * 4;
    int nr  = (ry == RYB - 1) ? 2 : 4;     // output rows this block
    int rows = nr + 2;                     // input strip rows
    int b = img & 1;
    int t = threadIdx.x;

    // stage weights (95,232 B = 23,808 dwords)
    {
        unsigned* dst = (unsigned*)wlds;
        for (int i = t; i < 23808; i += 256) dst[i] = wb_g[i];
    }
    // theta for this image
    const float* th = theta + img * 6;
    float t00 = th[0], t01 = th[1], t02 = th[2];
    float t10 = th[3], t11 = th[4], t12 = th[5];

    // sample strip rows sy = oy0 .. oy0+rows-1 for all 62 channels
    const float* hm = heatmap + (size_t)b * CHM * HW * HW;
    for (int v = t; v < rows * CHM * 40; v += 256) {
        int r = v / (CHM * 40);
        int rem = v - r * (CHM * 40);
        int ic = rem / 40;
        int sx = rem - ic * 40;
        int sy = oy0 + r;
        float gx = (2 * sx + 1) * 0.025f - 1.f;
        float gy = (2 * sy + 1) * 0.025f - 1.f;
        float X = fmaf(t00, gx, fmaf(t01, gy, t02));
        float Y = fmaf(t10, gx, fmaf(t11, gy, t12));
        float ix = fmaf(X, 90.f, 89.5f);
        float iy = fmaf(Y, 90.f, 89.5f);
        float xf = floorf(ix), yf = floorf(iy);
        float wx1 = ix - xf, wy1 = iy - yf;
        int x0i = (int)xf, y0i = (int)yf;
        const float* base = hm + (size_t)ic * HW * HW;
        float acc = 0.f;
        {   // 4 corners, zero padding
            float w00 = (1.f - wx1) * (1.f - wy1), w10 = wx1 * (1.f - wy1);
            float w01 = (1.f - wx1) * wy1,         w11 = wx1 * wy1;
            bool xi0 = (x0i >= 0) & (x0i < HW), xi1 = (x0i + 1 >= 0) & (x0i + 1 < HW);
            bool yi0 = (y0i >= 0) & (y0i < HW), yi1 = (y0i + 1 >= 0) & (y0i + 1 < HW);
            if (xi0 & yi0) acc = fmaf(w00, base[y0i * HW + x0i], acc);
            if (xi1 & yi0) acc = fmaf(w10, base[y0i * HW + x0i + 1], acc);
            if (xi0 & yi1) acc = fmaf(w01, base[(y0i + 1) * HW + x0i], acc);
            if (xi1 & yi1) acc = fmaf(w11, base[(y0i + 1) * HW + x0i + 1], acc);
        }
        strip[(r * CHM + ic) * 40 + sx] = __float2bfloat16(acc);
    }
    __syncthreads();

    // conv: wave = 64 output channels, wave id = x-chunk {0,10,20,30}
    int oc = t & 63;
    int xc = t >> 6;
    int x0 = xc * 10;
    int sz = (xc == 3) ? 8 : 10;

    float acc[4][10];
#pragma unroll
    for (int r = 0; r < 4; ++r)
#pragma unroll
        for (int i = 0; i < 10; ++i) acc[r][i] = 0.f;

    for (int ic = 0; ic < CHM; ++ic) {
        float w[3][3];
#pragma unroll
        for (int ky = 0; ky < 3; ++ky) {
            uint2 wv = *(const uint2*)&wlds[(size_t)((ic * 3 + ky) * 64 + oc) * 4];
            w[ky][0] = bflo(wv.x);
            w[ky][1] = bfhi(wv.x);
            w[ky][2] = bflo(wv.y);
        }
#pragma unroll
        for (int sr = 0; sr < 6; ++sr) {
            if (sr >= rows) break;                 // wave-uniform
            float f[12];
            const unsigned* rowp = (const unsigned*)&strip[(sr * CHM + ic) * 40 + x0];
#pragma unroll
            for (int j = 0; j < 6; ++j) {          // broadcast reads (all lanes same addr)
                unsigned u = rowp[j];
                f[2 * j]     = bflo(u);
                f[2 * j + 1] = bfhi(u);
            }
#pragma unroll
            for (int ky = 0; ky < 3; ++ky) {
                int r = sr - ky;
                if (r >= 0 && r < nr) {
#pragma unroll
                    for (int i = 0; i < 10; ++i) {
                        acc[r][i] = fmaf(w[ky][0], f[i],     acc[r][i]);
                        acc[r][i] = fmaf(w[ky][1], f[i + 1], acc[r][i]);
                        acc[r][i] = fmaf(w[ky][2], f[i + 2], acc[r][i]);
                    }
                }
            }
        }
    }

    float bia = bias[oc];
    if constexpr (MODE == 2) {
        float a = ab[oc * 2], bb = ab[oc * 2 + 1];
        float pp = 0.f;
        for (int r = 0; r < nr; ++r)
            for (int i = 0; i < sz; ++i)
                pp += fmaxf(fmaf(a, acc[r][i] + bia, bb), 0.f);
        red[xc * 64 + oc] = pp;
        __syncthreads();
        if (t < 64)
            poolp[(size_t)bid * 64 + t] = red[t] + red[64 + t] + red[128 + t] + red[192 + t];
    } else {
        float s = 0.f, s2 = 0.f;
        for (int r = 0; r < nr; ++r)
            for (int i = 0; i < sz; ++i) {
                float val = acc[r][i] + bia;
                if constexpr (MODE == 0) {
                    size_t p = (size_t)img * Pp + (oy0 + r) * OH + x0 + i;
                    conv_out[p * 64 + oc] = __float2bfloat16(val);
                }
                s += val;
                s2 = fmaf(val, val, s2);
            }
        red[(xc * 64 + oc) * 2]     = s;
        red[(xc * 64 + oc) * 2 + 1] = s2;
        __syncthreads();
        if (t < 64) {
            float S = 0.f, S2 = 0.f;
#pragma unroll
            for (int x = 0; x < 4; ++x) {
                S  += red[(x * 64 + t) * 2];
                S2 += red[(x * 64 + t) * 2 + 1];
            }
            partials[((size_t)bid * 64 + t) * 2]     = S;
            partials[((size_t)bid * 64 + t) * 2 + 1] = S2;
        }
    }
}

// ============ K3b: reduce per-block sums -> BN a,b per channel ============
__global__ void k_stats(const float* __restrict__ partials, const float* __restrict__ gamma,
                        const float* __restrict__ beta, float* __restrict__ ab) {
    __shared__ float red[256][2];
    int oc = blockIdx.x, t = threadIdx.x;
    float S = 0.f, S2 = 0.f;
    for (int j = t; j < NBLK; j += 256) {
        S  += partials[((size_t)j * 64 + oc) * 2];
        S2 += partials[((size_t)j * 64 + oc) * 2 + 1];
    }
    red[t][0] = S; red[t][1] = S2;
    __syncthreads();
    for (int off = 128; off >= 1; off >>= 1) {
        if (t < off) { red[t][0] += red[t + off][0]; red[t][1] += red[t + off][1]; }
        __syncthreads();
    }
    if (t == 0) {
        float cnt = (float)NIMG * (float)Pp;
        float mu  = red[0][0] / cnt;
        float var = red[0][1] / cnt - mu * mu;
        float a = gamma[oc] * rsqrtf(var + 1e-5f);
        ab[oc * 2] = a;
        ab[oc * 2 + 1] = beta[oc] - mu * a;
    }
}

// ============ K4r: (store path) BN+ReLU+pool from conv_out + final 1x1 ============
__global__ __launch_bounds__(256) void k_pool_reload(
    const __hip_bfloat16* __restrict__ conv_out, const float* __restrict__ ab,
    const float* __restrict__ w2, const float* __restrict__ b2, float* __restrict__ out) {
    __shared__ float red[4][64], pooled[64], red2[2][64];
    int img = blockIdx.x, t = threadIdx.x;
    int oc = t & 63, pc = t >> 6;
    float a = ab[oc * 2], bb = ab[oc * 2 + 1];
    float pp = 0.f;
    const __hip_bfloat16* src = conv_out + (size_t)img * Pp * 64;
    for (int p = pc; p < Pp; p += 4) {
        float v = __bfloat162float(src[(size_t)p * 64 + oc]);
        pp += fmaxf(fmaf(a, v, bb), 0.f);
    }
    red[pc][oc] = pp;
    __syncthreads();
    if (t < 64) pooled[t] = (red[0][t] + red[1][t] + red[2][t] + red[3][t]) * (1.f / (float)Pp);
    __syncthreads();
    if (t < 128) {
        int j = t >> 6, c = t & 63;
        red2[j][c] = pooled[c] * w2[j * 64 + c];
    }
    __syncthreads();
    if (t < 2) {
        float s = b2[t];
        for (int c = 0; c < 64; ++c) s += red2[t][c];
        out[img * 2 + t] = s;
    }
}

// ============ K5: (recompute path) finish pool + final 1x1 ============
__global__ void k_pool_finish(const float* __restrict__ poolp, const float* __restrict__ w2,
                              const float* __restrict__ b2, float* __restrict__ out) {
    __shared__ float pooled[64];
    int img = blockIdx.x, t = threadIdx.x;   // 64 threads
    float s = 0.f;
    for (int r = 0; r < RYB; ++r) s += poolp[((size_t)img * RYB + r) * 64 + t];
    pooled[t] = s * (1.f / (float)Pp);
    __syncthreads();
    if (t < 2) {
        float o = b2[t];
        for (int c = 0; c < 64; ++c) o = fmaf(pooled[c], w2[t * 64 + c], o);
        out[img * 2 + t] = o;
    }
}

// ============ host ============
extern "C" void kernel_launch(void* const* d_in, const int* in_sizes, int n_in,
                              void* d_out, int out_size, void* d_ws, size_t ws_size,
                              hipStream_t stream) {
    const float* q   = (const float*)d_in[0];
    const float* hm  = (const float*)d_in[1];
    const float* w1  = (const float*)d_in[2];
    const float* b1  = (const float*)d_in[3];
    const float* w2  = (const float*)d_in[4];
    const float* b2  = (const float*)d_in[5];
    const float* w3  = (const float*)d_in[6];
    const float* b3  = (const float*)d_in[7];
    const float* cw  = (const float*)d_in[8];
    const float* cb  = (const float*)d_in[9];
    const float* gam = (const float*)d_in[10];
    const float* bet = (const float*)d_in[11];
    const float* c2w = (const float*)d_in[12];
    const float* c2b = (const float*)d_in[13];
    float* out = (float*)d_out;
    char* ws = (char*)d_ws;

    float* theta = (float*)(ws + OFF_THETA);
    unsigned* wb = (unsigned*)(ws + OFF_WB);
    float* partials = (float*)(ws + OFF_PART);
    float* ab = (float*)(ws + OFF_AB);
    float* poolp = (float*)(ws + OFF_POOLP);
    __hip_bfloat16* conv_out = (__hip_bfloat16*)(ws + OFF_CONV);

    bool store = ws_size >= WS_STORE_NEED;

    // allow >64KB dynamic LDS (ignore errors; harmless if unnecessary)
    (void)hipFuncSetAttribute((const void*)k_conv<0>, hipFuncAttributeMaxDynamicSharedMemorySize, SM_TOTAL);
    (void)hipFuncSetAttribute((const void*)k_conv<1>, hipFuncAttributeMaxDynamicSharedMemorySize, SM_TOTAL);
    (void)hipFuncSetAttribute((const void*)k_conv<2>, hipFuncAttributeMaxDynamicSharedMemorySize, SM_TOTAL);

    k_theta<<<NIMG, 64, 0, stream>>>(q, w1, b1, w2, b2, w3, b3, theta);
    k_wcvt<<<(CHM * 3 * 64 + 255) / 256, 256, 0, stream>>>(cw, (__hip_bfloat16*)wb);

    if (store) {
        k_conv<0><<<NBLK, 256, SM_TOTAL, stream>>>(hm, theta, wb, cb, nullptr, partials, conv_out, nullptr);
        k_stats<<<64, 256, 0, stream>>>(partials, gam, bet, ab);
        k_pool_reload<<<NIMG, 256, 0, stream>>>(conv_out, ab, c2w, c2b, out);
    } else {
        k_conv<1><<<NBLK, 256, SM_TOTAL, stream>>>(hm, theta, wb, cb, nullptr, partials, nullptr, nullptr);
        k_stats<<<64, 256, 0, stream>>>(partials, gam, bet, ab);
        k_conv<2><<<NBLK, 256, SM_TOTAL, stream>>>(hm, theta, wb, cb, ab, nullptr, nullptr, poolp);
        k_pool_finish<<<NIMG, 64, 0, stream>>>(poolp, c2w, c2b, out);
    }
}

// Round 2
// 768.743 us; speedup vs baseline: 3.4299x; 3.4299x over previous
//
#include <hip/hip_runtime.h>

// ---------------- problem constants ----------------
constexpr int Bc = 2, Nc = 256, CHM = 62;
constexpr int HW = 180;            // heatmap H=W
constexpr int OH = 38;             // conv out H=W
constexpr int Pp = OH * OH;        // 1444 positions
constexpr int NIMG = Bc * Nc;      // 512 images (n-major: img = n*B + b)
constexpr int R2 = 8;              // output rows per conv block
constexpr int NRB2 = 5;            // row-blocks per image (8,8,8,8,6)
constexpr int NBLK2 = NIMG * NRB2; // 2560
constexpr int KP = 576;            // padded K = 9 taps * 64 ch

// ---------------- ws layout (bytes) ----------------
constexpr size_t OFF_THETA = 0;            // 512*6*4        = 12,288
constexpr size_t OFF_WB    = 16384;        // 64*576*2 bf16  = 73,728
constexpr size_t OFF_PART  = 131072;       // 2560*64*2*4    = 1,310,720
constexpr size_t OFF_AB    = 2752512;      // 64*2*4         = 512
constexpr size_t OFF_CONV  = 4194304;      // 512*1444*64*2  = 94,633,984

typedef __attribute__((ext_vector_type(8))) short  short8;
typedef __attribute__((ext_vector_type(8))) __bf16 bf16x8;
typedef __attribute__((ext_vector_type(4))) float  f32x4;

__device__ __forceinline__ bf16x8 bc(short8 v) { return __builtin_bit_cast(bf16x8, v); }

// ============ K1: fc_loc MLP -> theta[img][6], img = n*B + b ============
__global__ void k_theta(const float* __restrict__ q,
                        const float* __restrict__ w1, const float* __restrict__ b1,
                        const float* __restrict__ w2, const float* __restrict__ b2,
                        const float* __restrict__ w3, const float* __restrict__ b3,
                        float* __restrict__ theta) {
    __shared__ float qv[256], h1[64], h2[64];
    int qi = blockIdx.x;           // = b*N + n
    int t  = threadIdx.x;          // 64 threads
    int b = qi >> 8, n = qi & 255;
    const float* qrow = q + qi * 256;
    for (int i = t; i < 256; i += 64) qv[i] = qrow[i];
    __syncthreads();
    float s = b1[t];
    const float* wr = w1 + t * 256;
    for (int i = 0; i < 256; ++i) s = fmaf(qv[i], wr[i], s);
    h1[t] = fmaxf(s, 0.f);
    __syncthreads();
    s = b2[t]; wr = w2 + t * 64;
    for (int i = 0; i < 64; ++i) s = fmaf(h1[i], wr[i], s);
    h2[t] = fmaxf(s, 0.f);
    __syncthreads();
    if (t < 6) {
        s = b3[t]; wr = w3 + t * 64;
        for (int i = 0; i < 64; ++i) s = fmaf(h2[i], wr[i], s);
        theta[(n * Bc + b) * 6 + t] = s;
    }
}

// ============ K2: conv1 weights fp32 [oc][ic][ky][kx] -> bf16 wb[n][k], k=(tap*64+ic), ic padded ============
__global__ void k_wcvt2(const float* __restrict__ w, __bf16* __restrict__ wb) {
    int idx = blockIdx.x * 256 + threadIdx.x;      // over 64*576
    if (idx < 64 * KP) {
        int n = idx / KP, k = idx - n * KP;
        int tap = k >> 6, ic = k & 63;
        float v = (ic < CHM) ? w[(n * CHM + ic) * 9 + tap] : 0.f;
        wb[idx] = (__bf16)v;
    }
}

// ============ K3: fused sample + MFMA implicit-GEMM conv ============
// strip LDS: [rows<=10][x:40][ic:64] bf16, element swizzle e ^= (x&7)<<3  (byte ^= (x&7)<<4)
__global__ __launch_bounds__(256, 3) void k_conv2(
    const float* __restrict__ heatmap, const float* __restrict__ theta,
    const __bf16* __restrict__ wb, const float* __restrict__ bias,
    float* __restrict__ partials, __bf16* __restrict__ conv_out) {
    __shared__ char smem[51200];                 // 10*40*64*2

    int bid = blockIdx.x;
    int img = bid / NRB2, ry = bid % NRB2;
    int oy0 = ry * R2;
    int nr  = (ry == NRB2 - 1) ? 6 : 8;          // output rows this block
    int t = threadIdx.x;
    int lane = t & 63, wv = t >> 6;
    int col = lane & 15, chunk = lane >> 4;

    // ---- B fragments straight from global into registers (n-tile = wv) ----
    short8 bfr[18];
    {
        int n = wv * 16 + col;
        const char* wp = (const char*)wb + (size_t)n * (KP * 2) + chunk * 16;
#pragma unroll
        for (int s = 0; s < 18; ++s)
            bfr[s] = *(const short8*)(wp + s * 64);
    }

    // ---- sampling: wave handles one (r,x) per iteration, lane = channel ----
    const float* th = theta + img * 6;
    float t00 = th[0], t01 = th[1], t02 = th[2];
    float t10 = th[3], t11 = th[4], t12 = th[5];
    int b = img & 1;
    const float* cbase = heatmap + ((size_t)b * CHM + (lane < CHM ? lane : CHM - 1)) * (HW * HW);
    int rows = nr + 2;
    for (int rx = wv; rx < rows * 40; rx += 4) {
        int r = rx / 40, x = rx - r * 40;
        float gx = (2 * x + 1) * 0.025f - 1.f;
        float gy = (2 * (oy0 + r) + 1) * 0.025f - 1.f;
        float X = fmaf(t00, gx, fmaf(t01, gy, t02));
        float Y = fmaf(t10, gx, fmaf(t11, gy, t12));
        float ix = fmaf(X, 90.f, 89.5f);
        float iy = fmaf(Y, 90.f, 89.5f);
        float xf = floorf(ix), yf = floorf(iy);
        float wx1 = ix - xf, wy1 = iy - yf;
        int x0 = (int)xf, y0 = (int)yf;
        float w00 = (1.f - wx1) * (1.f - wy1), w10 = wx1 * (1.f - wy1);
        float w01 = (1.f - wx1) * wy1,         w11 = wx1 * wy1;
        bool xi0 = (unsigned)x0 < (unsigned)HW, xi1 = (unsigned)(x0 + 1) < (unsigned)HW;
        bool yi0 = (unsigned)y0 < (unsigned)HW, yi1 = (unsigned)(y0 + 1) < (unsigned)HW;
        float acc = 0.f;
        if (lane < CHM) {
            if (xi0 & yi0) acc = fmaf(w00, cbase[y0 * HW + x0], acc);
            if (xi1 & yi0) acc = fmaf(w10, cbase[y0 * HW + x0 + 1], acc);
            if (xi0 & yi1) acc = fmaf(w01, cbase[(y0 + 1) * HW + x0], acc);
            if (xi1 & yi1) acc = fmaf(w11, cbase[(y0 + 1) * HW + x0 + 1], acc);
        }
        int e = (rx << 6) | (lane ^ ((x & 7) << 3));
        *(__bf16*)(smem + 2 * e) = (__bf16)acc;
    }
    __syncthreads();

    // ---- MFMA m-loop: each wave owns 16 output channels (n-tile), loops m-tiles ----
    float bia = bias[wv * 16 + col];
    float ssum = 0.f, ssq = 0.f;
    int mA = col;                                 // A-operand row = lane&15
    int lim = nr * 38 - 1;
    int nt = (nr * 38 + 15) >> 4;                 // 19 or 15
    __bf16* cobase = conv_out + ((size_t)img * Pp + oy0 * 38) * 64 + (wv * 16 + col);
    int cb = chunk << 4;

    for (int tt = 0; tt < nt; tt += 2) {
        f32x4 acc0 = {0.f, 0.f, 0.f, 0.f}, acc1 = {0.f, 0.f, 0.f, 0.f};
        bool has1 = (tt + 1) < nt;
        int p0 = tt * 16 + mA;       p0 = p0 > lim ? lim : p0;
        int p1 = (tt + 1) * 16 + mA; p1 = p1 > lim ? lim : p1;
        int oyl0 = p0 / 38, ox0 = p0 - oyl0 * 38;
        int oyl1 = p1 / 38, ox1 = p1 - oyl1 * 38;
        int rb0 = oyl0 * 5120, rb1 = oyl1 * 5120;
        int xb0[3], xs0[3], xb1[3], xs1[3];
#pragma unroll
        for (int kk = 0; kk < 3; ++kk) {
            xb0[kk] = (ox0 + kk) * 128; xs0[kk] = ((ox0 + kk) & 7) << 4;
            xb1[kk] = (ox1 + kk) * 128; xs1[kk] = ((ox1 + kk) & 7) << 4;
        }
#pragma unroll
        for (int s = 0; s < 18; ++s) {
            const int tap = s >> 1;
            const int ky = tap / 3, kx = tap % 3;
            const int hb = (s & 1) << 6;
            int a0 = rb0 + ky * 5120 + xb0[kx] + ((hb | cb) ^ xs0[kx]);
            short8 av0 = *(const short8*)(smem + a0);
            acc0 = __builtin_amdgcn_mfma_f32_16x16x32_bf16(bc(av0), bc(bfr[s]), acc0, 0, 0, 0);
            if (has1) {
                int a1 = rb1 + ky * 5120 + xb1[kx] + ((hb | cb) ^ xs1[kx]);
                short8 av1 = *(const short8*)(smem + a1);
                acc1 = __builtin_amdgcn_mfma_f32_16x16x32_bf16(bc(av1), bc(bfr[s]), acc1, 0, 0, 0);
            }
        }
        // epilogue: C row = chunk*4 + reg, col = lane&15 (channel)
#pragma unroll
        for (int r2 = 0; r2 < 4; ++r2) {
            int pl = tt * 16 + chunk * 4 + r2;
            if (pl <= lim) {
                float v = acc0[r2] + bia;
                cobase[(size_t)pl * 64] = (__bf16)v;
                ssum += v; ssq = fmaf(v, v, ssq);
            }
        }
        if (has1) {
#pragma unroll
            for (int r2 = 0; r2 < 4; ++r2) {
                int pl = (tt + 1) * 16 + chunk * 4 + r2;
                if (pl <= lim) {
                    float v = acc1[r2] + bia;
                    cobase[(size_t)pl * 64] = (__bf16)v;
                    ssum += v; ssq = fmaf(v, v, ssq);
                }
            }
        }
    }

    // cross-lane: sum lanes {l, l^16, l^32, l^48} (same output col)
    ssum += __shfl_xor(ssum, 16); ssum += __shfl_xor(ssum, 32);
    ssq  += __shfl_xor(ssq, 16);  ssq  += __shfl_xor(ssq, 32);
    if (lane < 16) {
        partials[((size_t)bid * 64 + wv * 16 + lane) * 2]     = ssum;
        partials[((size_t)bid * 64 + wv * 16 + lane) * 2 + 1] = ssq;
    }
}

// ============ K3b: reduce per-block sums -> BN a,b per channel ============
__global__ void k_stats(const float* __restrict__ partials, const float* __restrict__ gamma,
                        const float* __restrict__ beta, float* __restrict__ ab) {
    __shared__ float red[256][2];
    int oc = blockIdx.x, t = threadIdx.x;
    float S = 0.f, S2 = 0.f;
    for (int j = t; j < NBLK2; j += 256) {
        S  += partials[((size_t)j * 64 + oc) * 2];
        S2 += partials[((size_t)j * 64 + oc) * 2 + 1];
    }
    red[t][0] = S; red[t][1] = S2;
    __syncthreads();
    for (int off = 128; off >= 1; off >>= 1) {
        if (t < off) { red[t][0] += red[t + off][0]; red[t][1] += red[t + off][1]; }
        __syncthreads();
    }
    if (t == 0) {
        float cnt = (float)NIMG * (float)Pp;
        float mu  = red[0][0] / cnt;
        float var = red[0][1] / cnt - mu * mu;
        float a = gamma[oc] * rsqrtf(var + 1e-5f);
        ab[oc * 2] = a;
        ab[oc * 2 + 1] = beta[oc] - mu * a;
    }
}

// ============ K4: BN+ReLU+pool from conv_out + final 1x1 ============
__global__ __launch_bounds__(256) void k_pool_reload(
    const __bf16* __restrict__ conv_out, const float* __restrict__ ab,
    const float* __restrict__ w2, const float* __restrict__ b2, float* __restrict__ out) {
    __shared__ float red[4][64], pooled[64], red2[2][64];
    int img = blockIdx.x, t = threadIdx.x;
    int oc = t & 63, pc = t >> 6;
    float a = ab[oc * 2], bb = ab[oc * 2 + 1];
    float pp = 0.f;
    const __bf16* src = conv_out + (size_t)img * Pp * 64;
    for (int p = pc; p < Pp; p += 4) {
        float v = (float)src[(size_t)p * 64 + oc];
        pp += fmaxf(fmaf(a, v, bb), 0.f);
    }
    red[pc][oc] = pp;
    __syncthreads();
    if (t < 64) pooled[t] = (red[0][t] + red[1][t] + red[2][t] + red[3][t]) * (1.f / (float)Pp);
    __syncthreads();
    if (t < 128) {
        int j = t >> 6, c = t & 63;
        red2[j][c] = pooled[c] * w2[j * 64 + c];
    }
    __syncthreads();
    if (t < 2) {
        float s = b2[t];
        for (int c = 0; c < 64; ++c) s += red2[t][c];
        out[img * 2 + t] = s;
    }
}

// ============ host ============
extern "C" void kernel_launch(void* const* d_in, const int* in_sizes, int n_in,
                              void* d_out, int out_size, void* d_ws, size_t ws_size,
                              hipStream_t stream) {
    const float* q   = (const float*)d_in[0];
    const float* hm  = (const float*)d_in[1];
    const float* w1  = (const float*)d_in[2];
    const float* b1  = (const float*)d_in[3];
    const float* w2  = (const float*)d_in[4];
    const float* b2  = (const float*)d_in[5];
    const float* w3  = (const float*)d_in[6];
    const float* b3  = (const float*)d_in[7];
    const float* cw  = (const float*)d_in[8];
    const float* cb  = (const float*)d_in[9];
    const float* gam = (const float*)d_in[10];
    const float* bet = (const float*)d_in[11];
    const float* c2w = (const float*)d_in[12];
    const float* c2b = (const float*)d_in[13];
    float* out = (float*)d_out;
    char* ws = (char*)d_ws;

    float* theta    = (float*)(ws + OFF_THETA);
    __bf16* wb      = (__bf16*)(ws + OFF_WB);
    float* partials = (float*)(ws + OFF_PART);
    float* ab       = (float*)(ws + OFF_AB);
    __bf16* conv_out = (__bf16*)(ws + OFF_CONV);

    k_theta<<<NIMG, 64, 0, stream>>>(q, w1, b1, w2, b2, w3, b3, theta);
    k_wcvt2<<<(64 * KP + 255) / 256, 256, 0, stream>>>(cw, wb);
    k_conv2<<<NBLK2, 256, 0, stream>>>(hm, theta, wb, cb, partials, conv_out);
    k_stats<<<64, 256, 0, stream>>>(partials, gam, bet, ab);
    k_pool_reload<<<NIMG, 256, 0, stream>>>(conv_out, ab, c2w, c2b, out);
}

// Round 3
// 331.733 us; speedup vs baseline: 7.9483x; 2.3174x over previous
//
#include <hip/hip_runtime.h>

// ---------------- problem constants ----------------
constexpr int Bc = 2, Nc = 256, CHM = 62;
constexpr int HW = 180;            // heatmap H=W
constexpr int OH = 38;             // conv out H=W
constexpr int Pp = OH * OH;        // 1444 positions
constexpr int NIMG = Bc * Nc;      // 512 images (n-major: img = n*B + b)
constexpr int R2 = 8;              // output rows per conv block
constexpr int NRB2 = 5;            // row-blocks per image (8,8,8,8,6)
constexpr int NBLK2 = NIMG * NRB2; // 2560
constexpr int KP = 576;            // padded K = 9 taps * 64 ch

// ---------------- ws layout (bytes) ----------------
constexpr size_t OFF_THETA = 0;            // 512*6*4        = 12,288
constexpr size_t OFF_WB    = 16384;        // 64*576*2 bf16  = 73,728
constexpr size_t OFF_PART  = 131072;       // 2560*64*2*4    = 1,310,720
constexpr size_t OFF_AB    = 2752512;      // 64*2*4         = 512
constexpr size_t OFF_CONV  = 4194304;      // 512*1444*64*2  = 94,633,984

typedef __attribute__((ext_vector_type(8))) short  short8;
typedef __attribute__((ext_vector_type(8))) __bf16 bf16x8;
typedef __attribute__((ext_vector_type(4))) float  f32x4;

__device__ __forceinline__ bf16x8 bc(short8 v) { return __builtin_bit_cast(bf16x8, v); }

// ============ K1: fc_loc MLP -> theta[img][6], img = n*B + b ============
__global__ void k_theta(const float* __restrict__ q,
                        const float* __restrict__ w1, const float* __restrict__ b1,
                        const float* __restrict__ w2, const float* __restrict__ b2,
                        const float* __restrict__ w3, const float* __restrict__ b3,
                        float* __restrict__ theta) {
    __shared__ float qv[256], h1[64], h2[64];
    int qi = blockIdx.x;           // = b*N + n
    int t  = threadIdx.x;          // 64 threads
    int b = qi >> 8, n = qi & 255;
    const float* qrow = q + qi * 256;
    for (int i = t; i < 256; i += 64) qv[i] = qrow[i];
    __syncthreads();
    float s = b1[t];
    const float* wr = w1 + t * 256;
    for (int i = 0; i < 256; ++i) s = fmaf(qv[i], wr[i], s);
    h1[t] = fmaxf(s, 0.f);
    __syncthreads();
    s = b2[t]; wr = w2 + t * 64;
    for (int i = 0; i < 64; ++i) s = fmaf(h1[i], wr[i], s);
    h2[t] = fmaxf(s, 0.f);
    __syncthreads();
    if (t < 6) {
        s = b3[t]; wr = w3 + t * 64;
        for (int i = 0; i < 64; ++i) s = fmaf(h2[i], wr[i], s);
        theta[(n * Bc + b) * 6 + t] = s;
    }
}

// ============ K2: conv1 weights fp32 [oc][ic][ky][kx] -> bf16 wb[n][k], k=(tap*64+ic) ============
__global__ void k_wcvt2(const float* __restrict__ w, __bf16* __restrict__ wb) {
    int idx = blockIdx.x * 256 + threadIdx.x;      // over 64*576
    if (idx < 64 * KP) {
        int n = idx / KP, k = idx - n * KP;
        int tap = k >> 6, ic = k & 63;
        float v = (ic < CHM) ? w[(n * CHM + ic) * 9 + tap] : 0.f;
        wb[idx] = (__bf16)v;
    }
}

// ============ K3: fused sample + MFMA implicit-GEMM conv ============
// strip LDS: [rx<=10*40][ic:64] bf16, 16B-granular swizzle: elem ^= (x&7)<<3
// gather: lane = position (coalesced within one channel plane), loop channels
// block order: bid = ry*512 + b*256 + n  (ry-major -> concurrent blocks share
// a ~3.4MB heatmap strip region -> L2-resident)
#define PREP(S, PIDX, VLD) \
    int o00##S, o10##S, o01##S, o11##S, eb##S, sw##S; \
    float w00##S, w10##S, w01##S, w11##S; \
    { int p = (PIDX); \
      int r = p / 40, x = p - r * 40; \
      float gx = (2 * x + 1) * 0.025f - 1.f; \
      float gy = (2 * (oy0 + r) + 1) * 0.025f - 1.f; \
      float X = fmaf(t00, gx, fmaf(t01, gy, t02)); \
      float Y = fmaf(t10, gx, fmaf(t11, gy, t12)); \
      float ix = fmaf(X, 90.f, 89.5f), iy = fmaf(Y, 90.f, 89.5f); \
      float xf = floorf(ix), yf = floorf(iy); \
      float fx = ix - xf, fy = iy - yf; \
      int x0 = (int)xf, y0 = (int)yf; \
      bool xi0 = (unsigned)x0 < (unsigned)HW, xi1 = (unsigned)(x0 + 1) < (unsigned)HW; \
      bool yi0 = (unsigned)y0 < (unsigned)HW, yi1 = (unsigned)(y0 + 1) < (unsigned)HW; \
      float vm = (VLD) ? 1.f : 0.f; \
      w00##S = (xi0 & yi0) ? (1.f - fx) * (1.f - fy) * vm : 0.f; \
      w10##S = (xi1 & yi0) ? fx * (1.f - fy) * vm : 0.f; \
      w01##S = (xi0 & yi1) ? (1.f - fx) * fy * vm : 0.f; \
      w11##S = (xi1 & yi1) ? fx * fy * vm : 0.f; \
      o00##S = (xi0 & yi0) ? y0 * HW + x0 : 0; \
      o10##S = (xi1 & yi0) ? y0 * HW + x0 + 1 : 0; \
      o01##S = (xi0 & yi1) ? (y0 + 1) * HW + x0 : 0; \
      o11##S = (xi1 & yi1) ? (y0 + 1) * HW + x0 + 1 : 0; \
      eb##S = p << 6; sw##S = (x & 7) << 3; \
    }

__global__ __launch_bounds__(256, 3) void k_conv2(
    const float* __restrict__ heatmap, const float* __restrict__ theta,
    const __bf16* __restrict__ wb, const float* __restrict__ bias,
    float* __restrict__ partials, __bf16* __restrict__ conv_out) {
    __shared__ char smem[51200];                 // 10*40*64*2

    int bid = blockIdx.x;
    int n = bid & 255, bsel = (bid >> 8) & 1, ry = bid >> 9;
    int img = n * Bc + bsel;
    int oy0 = ry * R2;
    int nr  = (ry == NRB2 - 1) ? 6 : 8;          // output rows this block
    int t = threadIdx.x;
    int lane = t & 63, wv = t >> 6;
    int col = lane & 15, chunk = lane >> 4;

    // ---- B fragments straight from global into registers (n-tile = wv) ----
    short8 bfr[18];
    {
        int nn = wv * 16 + col;
        const char* wp = (const char*)wb + (size_t)nn * (KP * 2) + chunk * 16;
#pragma unroll
        for (int s = 0; s < 18; ++s)
            bfr[s] = *(const short8*)(wp + s * 64);
    }

    // ---- sampling ----
    const float* th = theta + img * 6;
    float t00 = th[0], t01 = th[1], t02 = th[2];
    float t10 = th[3], t11 = th[4], t12 = th[5];
    const float* hmb = heatmap + (size_t)bsel * CHM * HW * HW;
    int rows = nr + 2, npos = rows * 40;

    bool pv1 = (t + 256) < npos;
    PREP(A, t, true)
    PREP(B, t + 256, pv1)
    char* sb0 = smem + 2 * ebA;
    char* sb1 = smem + 2 * ebB;

    auto dofetch = [&](int c, float& a0, float& a1) {
        const float* pl = hmb + c * (HW * HW);
        a0 = fmaf(w00A, pl[o00A], fmaf(w10A, pl[o10A], fmaf(w01A, pl[o01A], w11A * pl[o11A])));
        a1 = fmaf(w00B, pl[o00B], fmaf(w10B, pl[o10B], fmaf(w01B, pl[o01B], w11B * pl[o11B])));
    };

    for (int cg = 0; cg < 7; ++cg) {
        bf16x8 v0, v1;
#pragma unroll
        for (int j = 0; j < 8; ++j) {
            float a0, a1; dofetch(cg * 8 + j, a0, a1);
            v0[j] = (__bf16)a0; v1[j] = (__bf16)a1;
        }
        int so = cg * 8;
        *(bf16x8*)(sb0 + 2 * (so ^ swA)) = v0;
        if (pv1) *(bf16x8*)(sb1 + 2 * (so ^ swB)) = v1;
    }
    {   // tail group: channels 56..61 + 2 pad
        bf16x8 v0, v1;
#pragma unroll
        for (int j = 0; j < 6; ++j) {
            float a0, a1; dofetch(56 + j, a0, a1);
            v0[j] = (__bf16)a0; v1[j] = (__bf16)a1;
        }
        v0[6] = (__bf16)0.f; v0[7] = (__bf16)0.f;
        v1[6] = (__bf16)0.f; v1[7] = (__bf16)0.f;
        *(bf16x8*)(sb0 + 2 * (56 ^ swA)) = v0;
        if (pv1) *(bf16x8*)(sb1 + 2 * (56 ^ swB)) = v1;
    }
    __syncthreads();

    // ---- MFMA m-loop: each wave owns 16 output channels (n-tile), loops m-tiles ----
    float bia = bias[wv * 16 + col];
    float ssum = 0.f, ssq = 0.f;
    int mA = col;                                 // A-operand row = lane&15
    int lim = nr * 38 - 1;
    int nt = (nr * 38 + 15) >> 4;                 // 19 or 15
    __bf16* cobase = conv_out + ((size_t)img * Pp + oy0 * 38) * 64 + (wv * 16 + col);
    int cb = chunk << 4;

    for (int tt = 0; tt < nt; tt += 2) {
        f32x4 acc0 = {0.f, 0.f, 0.f, 0.f}, acc1 = {0.f, 0.f, 0.f, 0.f};
        bool has1 = (tt + 1) < nt;
        int p0 = tt * 16 + mA;       p0 = p0 > lim ? lim : p0;
        int p1 = (tt + 1) * 16 + mA; p1 = p1 > lim ? lim : p1;
        int oyl0 = p0 / 38, ox0 = p0 - oyl0 * 38;
        int oyl1 = p1 / 38, ox1 = p1 - oyl1 * 38;
        int rb0 = oyl0 * 5120, rb1 = oyl1 * 5120;
        int xb0[3], xs0[3], xb1[3], xs1[3];
#pragma unroll
        for (int kk = 0; kk < 3; ++kk) {
            xb0[kk] = (ox0 + kk) * 128; xs0[kk] = ((ox0 + kk) & 7) << 4;
            xb1[kk] = (ox1 + kk) * 128; xs1[kk] = ((ox1 + kk) & 7) << 4;
        }
#pragma unroll
        for (int s = 0; s < 18; ++s) {
            const int tap = s >> 1;
            const int ky = tap / 3, kx = tap % 3;
            const int hb = (s & 1) << 6;
            int a0 = rb0 + ky * 5120 + xb0[kx] + ((hb | cb) ^ xs0[kx]);
            short8 av0 = *(const short8*)(smem + a0);
            acc0 = __builtin_amdgcn_mfma_f32_16x16x32_bf16(bc(av0), bc(bfr[s]), acc0, 0, 0, 0);
            if (has1) {
                int a1 = rb1 + ky * 5120 + xb1[kx] + ((hb | cb) ^ xs1[kx]);
                short8 av1 = *(const short8*)(smem + a1);
                acc1 = __builtin_amdgcn_mfma_f32_16x16x32_bf16(bc(av1), bc(bfr[s]), acc1, 0, 0, 0);
            }
        }
        // epilogue: C row = chunk*4 + reg, col = lane&15 (channel)
#pragma unroll
        for (int r2 = 0; r2 < 4; ++r2) {
            int pl = tt * 16 + chunk * 4 + r2;
            if (pl <= lim) {
                float v = acc0[r2] + bia;
                cobase[(size_t)pl * 64] = (__bf16)v;
                ssum += v; ssq = fmaf(v, v, ssq);
            }
        }
        if (has1) {
#pragma unroll
            for (int r2 = 0; r2 < 4; ++r2) {
                int pl = (tt + 1) * 16 + chunk * 4 + r2;
                if (pl <= lim) {
                    float v = acc1[r2] + bia;
                    cobase[(size_t)pl * 64] = (__bf16)v;
                    ssum += v; ssq = fmaf(v, v, ssq);
                }
            }
        }
    }

    // cross-lane: sum lanes {l, l^16, l^32, l^48} (same output col)
    ssum += __shfl_xor(ssum, 16); ssum += __shfl_xor(ssum, 32);
    ssq  += __shfl_xor(ssq, 16);  ssq  += __shfl_xor(ssq, 32);
    if (lane < 16) {
        partials[((size_t)bid * 64 + wv * 16 + lane) * 2]     = ssum;
        partials[((size_t)bid * 64 + wv * 16 + lane) * 2 + 1] = ssq;
    }
}

// ============ K3b: reduce per-block sums -> BN a,b per channel ============
__global__ void k_stats(const float* __restrict__ partials, const float* __restrict__ gamma,
                        const float* __restrict__ beta, float* __restrict__ ab) {
    __shared__ float red[256][2];
    int oc = blockIdx.x, t = threadIdx.x;
    float S = 0.f, S2 = 0.f;
    for (int j = t; j < NBLK2; j += 256) {
        S  += partials[((size_t)j * 64 + oc) * 2];
        S2 += partials[((size_t)j * 64 + oc) * 2 + 1];
    }
    red[t][0] = S; red[t][1] = S2;
    __syncthreads();
    for (int off = 128; off >= 1; off >>= 1) {
        if (t < off) { red[t][0] += red[t + off][0]; red[t][1] += red[t + off][1]; }
        __syncthreads();
    }
    if (t == 0) {
        float cnt = (float)NIMG * (float)Pp;
        float mu  = red[0][0] / cnt;
        float var = red[0][1] / cnt - mu * mu;
        float a = gamma[oc] * rsqrtf(var + 1e-5f);
        ab[oc * 2] = a;
        ab[oc * 2 + 1] = beta[oc] - mu * a;
    }
}

// ============ K4: BN+ReLU+pool from conv_out + final 1x1 ============
__global__ __launch_bounds__(256) void k_pool_reload(
    const __bf16* __restrict__ conv_out, const float* __restrict__ ab,
    const float* __restrict__ w2, const float* __restrict__ b2, float* __restrict__ out) {
    __shared__ float red[4][64], pooled[64], red2[2][64];
    int img = blockIdx.x, t = threadIdx.x;
    int oc = t & 63, pc = t >> 6;
    float a = ab[oc * 2], bb = ab[oc * 2 + 1];
    float pp = 0.f;
    const __bf16* src = conv_out + (size_t)img * Pp * 64;
    for (int p = pc; p < Pp; p += 4) {
        float v = (float)src[(size_t)p * 64 + oc];
        pp += fmaxf(fmaf(a, v, bb), 0.f);
    }
    red[pc][oc] = pp;
    __syncthreads();
    if (t < 64) pooled[t] = (red[0][t] + red[1][t] + red[2][t] + red[3][t]) * (1.f / (float)Pp);
    __syncthreads();
    if (t < 128) {
        int j = t >> 6, c = t & 63;
        red2[j][c] = pooled[c] * w2[j * 64 + c];
    }
    __syncthreads();
    if (t < 2) {
        float s = b2[t];
        for (int c = 0; c < 64; ++c) s += red2[t][c];
        out[img * 2 + t] = s;
    }
}

// ============ host ============
extern "C" void kernel_launch(void* const* d_in, const int* in_sizes, int n_in,
                              void* d_out, int out_size, void* d_ws, size_t ws_size,
                              hipStream_t stream) {
    const float* q   = (const float*)d_in[0];
    const float* hm  = (const float*)d_in[1];
    const float* w1  = (const float*)d_in[2];
    const float* b1  = (const float*)d_in[3];
    const float* w2  = (const float*)d_in[4];
    const float* b2  = (const float*)d_in[5];
    const float* w3  = (const float*)d_in[6];
    const float* b3  = (const float*)d_in[7];
    const float* cw  = (const float*)d_in[8];
    const float* cb  = (const float*)d_in[9];
    const float* gam = (const float*)d_in[10];
    const float* bet = (const float*)d_in[11];
    const float* c2w = (const float*)d_in[12];
    const float* c2b = (const float*)d_in[13];
    float* out = (float*)d_out;
    char* ws = (char*)d_ws;

    float* theta    = (float*)(ws + OFF_THETA);
    __bf16* wb      = (__bf16*)(ws + OFF_WB);
    float* partials = (float*)(ws + OFF_PART);
    float* ab       = (float*)(ws + OFF_AB);
    __bf16* conv_out = (__bf16*)(ws + OFF_CONV);

    k_theta<<<NIMG, 64, 0, stream>>>(q, w1, b1, w2, b2, w3, b3, theta);
    k_wcvt2<<<(64 * KP + 255) / 256, 256, 0, stream>>>(cw, wb);
    k_conv2<<<NBLK2, 256, 0, stream>>>(hm, theta, wb, cb, partials, conv_out);
    k_stats<<<64, 256, 0, stream>>>(partials, gam, bet, ab);
    k_pool_reload<<<NIMG, 256, 0, stream>>>(conv_out, ab, c2w, c2b, out);
}

// Round 4
// 245.921 us; speedup vs baseline: 10.7218x; 1.3489x over previous
//
#include <hip/hip_runtime.h>

// ---------------- problem constants ----------------
constexpr int Bc = 2, Nc = 256, CHM = 62;
constexpr int HW = 180;            // heatmap H=W
constexpr int OH = 38;             // conv out H=W
constexpr int Pp = OH * OH;        // 1444 positions
constexpr int NIMG = Bc * Nc;      // 512 images (n-major: img = n*B + b)
constexpr int R2 = 8;              // output rows per conv block
constexpr int NRB2 = 5;            // row-blocks per image (8,8,8,8,6)
constexpr int NBLK2 = NIMG * NRB2; // 2560
constexpr int KP = 576;            // padded K = 9 taps * 64 ch

// ---------------- ws layout (bytes) ----------------
constexpr size_t OFF_THETA = 0;            // 512*6*4        = 12,288
constexpr size_t OFF_WB    = 16384;        // 64*576*2 bf16  = 73,728
constexpr size_t OFF_AB    = 90112;        // 64*2*4         = 512
constexpr size_t OFF_PART  = 131072;       // 2560*64*2*4    = 1,310,720
// legacy path:
constexpr size_t OFF_CONV_L = 4194304;     // 512*1444*64*2  = 94,633,984
// hmT path:
constexpr size_t OFF_HMT    = 1441792;     // 2*180*180*64*2 = 8,294,400
constexpr size_t OFF_CONV_H = 9736192;     // + 94,633,984   -> 104,370,176
constexpr size_t NEED_HMT   = 104370176;

typedef __attribute__((ext_vector_type(8))) short  short8;
typedef __attribute__((ext_vector_type(8))) __bf16 bf16x8;
typedef __attribute__((ext_vector_type(4))) float  f32x4;

__device__ __forceinline__ bf16x8 bc(short8 v) { return __builtin_bit_cast(bf16x8, v); }
__device__ __forceinline__ float tof(short s) {
    return __uint_as_float(((unsigned)(unsigned short)s) << 16);
}

// ============ K1: fc_loc MLP -> theta[img][6], img = n*B + b ============
__global__ void k_theta(const float* __restrict__ q,
                        const float* __restrict__ w1, const float* __restrict__ b1,
                        const float* __restrict__ w2, const float* __restrict__ b2,
                        const float* __restrict__ w3, const float* __restrict__ b3,
                        float* __restrict__ theta) {
    __shared__ float qv[256], h1[64], h2[64];
    int qi = blockIdx.x;           // = b*N + n
    int t  = threadIdx.x;          // 64 threads
    int b = qi >> 8, n = qi & 255;
    const float* qrow = q + qi * 256;
    for (int i = t; i < 256; i += 64) qv[i] = qrow[i];
    __syncthreads();
    float s = b1[t];
    const float* wr = w1 + t * 256;
    for (int i = 0; i < 256; ++i) s = fmaf(qv[i], wr[i], s);
    h1[t] = fmaxf(s, 0.f);
    __syncthreads();
    s = b2[t]; wr = w2 + t * 64;
    for (int i = 0; i < 64; ++i) s = fmaf(h1[i], wr[i], s);
    h2[t] = fmaxf(s, 0.f);
    __syncthreads();
    if (t < 6) {
        s = b3[t]; wr = w3 + t * 64;
        for (int i = 0; i < 64; ++i) s = fmaf(h2[i], wr[i], s);
        theta[(n * Bc + b) * 6 + t] = s;
    }
}

// ============ K2: conv1 weights fp32 [oc][ic][ky][kx] -> bf16 wb[n][k], k=(tap*64+ic) ============
__global__ void k_wcvt2(const float* __restrict__ w, __bf16* __restrict__ wb) {
    int idx = blockIdx.x * 256 + threadIdx.x;      // over 64*576
    if (idx < 64 * KP) {
        int n = idx / KP, k = idx - n * KP;
        int tap = k >> 6, ic = k & 63;
        float v = (ic < CHM) ? w[(n * CHM + ic) * 9 + tap] : 0.f;
        wb[idx] = (__bf16)v;
    }
}

// ============ K2b: heatmap [2][62][180][180] f32 -> hmT [2][180*180][64] bf16 ============
__global__ __launch_bounds__(192) void k_hmT(const float* __restrict__ hm, __bf16* __restrict__ hmT) {
    int by = blockIdx.x;           // b*180 + y
    int b = by / HW, y = by - b * HW;
    int x = threadIdx.x;
    if (x < HW) {
        const float* src = hm + (size_t)b * CHM * (HW * HW) + y * HW + x;
        __bf16* dst = hmT + ((size_t)(b * (HW * HW) + y * HW + x)) * 64;
#pragma unroll
        for (int g = 0; g < 8; ++g) {
            bf16x8 v;
#pragma unroll
            for (int j = 0; j < 8; ++j) {
                int c = g * 8 + j;
                v[j] = (c < CHM) ? (__bf16)src[(size_t)c * (HW * HW)] : (__bf16)0.f;
            }
            *(bf16x8*)(dst + g * 8) = v;
        }
    }
}

// ============ K3: fused sample + MFMA implicit-GEMM conv ============
// strip LDS: [rx<=10*40][ic:64] bf16, 16B-granular swizzle: elem ^= (x&7)<<3
// HMT=1: gather from channel-last bf16 hmT (dwordx4 per 8ch corner group)
// HMT=0: legacy per-channel-plane scalar gather
#define PREP(S, PIDX, VLD) \
    int o00##S, o10##S, o01##S, o11##S, eb##S, sw##S; \
    float w00##S, w10##S, w01##S, w11##S; \
    { int p = (PIDX); \
      int r = p / 40, x = p - r * 40; \
      float gx = (2 * x + 1) * 0.025f - 1.f; \
      float gy = (2 * (oy0 + r) + 1) * 0.025f - 1.f; \
      float X = fmaf(t00, gx, fmaf(t01, gy, t02)); \
      float Y = fmaf(t10, gx, fmaf(t11, gy, t12)); \
      float ix = fmaf(X, 90.f, 89.5f), iy = fmaf(Y, 90.f, 89.5f); \
      float xf = floorf(ix), yf = floorf(iy); \
      float fx = ix - xf, fy = iy - yf; \
      int x0 = (int)xf, y0 = (int)yf; \
      bool xi0 = (unsigned)x0 < (unsigned)HW, xi1 = (unsigned)(x0 + 1) < (unsigned)HW; \
      bool yi0 = (unsigned)y0 < (unsigned)HW, yi1 = (unsigned)(y0 + 1) < (unsigned)HW; \
      float vm = (VLD) ? 1.f : 0.f; \
      w00##S = (xi0 & yi0) ? (1.f - fx) * (1.f - fy) * vm : 0.f; \
      w10##S = (xi1 & yi0) ? fx * (1.f - fy) * vm : 0.f; \
      w01##S = (xi0 & yi1) ? (1.f - fx) * fy * vm : 0.f; \
      w11##S = (xi1 & yi1) ? fx * fy * vm : 0.f; \
      o00##S = (xi0 & yi0) ? y0 * HW + x0 : 0; \
      o10##S = (xi1 & yi0) ? y0 * HW + x0 + 1 : 0; \
      o01##S = (xi0 & yi1) ? (y0 + 1) * HW + x0 : 0; \
      o11##S = (xi1 & yi1) ? (y0 + 1) * HW + x0 + 1 : 0; \
      eb##S = p << 6; sw##S = (x & 7) << 3; \
    }

template<int HMT>
__global__ __launch_bounds__(256, 3) void k_conv2(
    const float* __restrict__ heatmap, const __bf16* __restrict__ hmT,
    const float* __restrict__ theta, const __bf16* __restrict__ wb,
    const float* __restrict__ bias, float* __restrict__ partials,
    __bf16* __restrict__ conv_out) {
    __shared__ char smem[51200];                 // 10*40*64*2

    int bid = blockIdx.x;
    int n = bid & 255, bsel = (bid >> 8) & 1, ry = bid >> 9;
    int img = n * Bc + bsel;
    int oy0 = ry * R2;
    int nr  = (ry == NRB2 - 1) ? 6 : 8;          // output rows this block
    int t = threadIdx.x;
    int lane = t & 63, wv = t >> 6;
    int col = lane & 15, chunk = lane >> 4;

    // ---- B fragments straight from global into registers (n-tile = wv) ----
    short8 bfr[18];
    {
        int nn = wv * 16 + col;
        const char* wp = (const char*)wb + (size_t)nn * (KP * 2) + chunk * 16;
#pragma unroll
        for (int s = 0; s < 18; ++s)
            bfr[s] = *(const short8*)(wp + s * 64);
    }

    // ---- sampling ----
    const float* th = theta + img * 6;
    float t00 = th[0], t01 = th[1], t02 = th[2];
    float t10 = th[3], t11 = th[4], t12 = th[5];
    int rows = nr + 2, npos = rows * 40;

    bool pv1 = (t + 256) < npos;
    PREP(A, t, true)
    PREP(B, t + 256, pv1)
    char* sb0 = smem + 2 * ebA;
    char* sb1 = smem + 2 * ebB;

    if constexpr (HMT) {
        const char* hb = (const char*)(hmT + (size_t)bsel * ((size_t)HW * HW * 64));
        const char* pA00 = hb + (size_t)o00A * 128;
        const char* pA10 = hb + (size_t)o10A * 128;
        const char* pA01 = hb + (size_t)o01A * 128;
        const char* pA11 = hb + (size_t)o11A * 128;
        const char* pB00 = hb + (size_t)o00B * 128;
        const char* pB10 = hb + (size_t)o10B * 128;
        const char* pB01 = hb + (size_t)o01B * 128;
        const char* pB11 = hb + (size_t)o11B * 128;
#pragma unroll
        for (int cg = 0; cg < 8; ++cg) {
            int off = cg * 16;
            short8 a00 = *(const short8*)(pA00 + off);
            short8 a10 = *(const short8*)(pA10 + off);
            short8 a01 = *(const short8*)(pA01 + off);
            short8 a11 = *(const short8*)(pA11 + off);
            bf16x8 v0;
#pragma unroll
            for (int j = 0; j < 8; ++j) {
                float f = w00A * tof(a00[j]);
                f = fmaf(w10A, tof(a10[j]), f);
                f = fmaf(w01A, tof(a01[j]), f);
                f = fmaf(w11A, tof(a11[j]), f);
                v0[j] = (__bf16)f;
            }
            *(bf16x8*)(sb0 + 2 * ((cg * 8) ^ swA)) = v0;
            if (pv1) {
                short8 b00 = *(const short8*)(pB00 + off);
                short8 b10 = *(const short8*)(pB10 + off);
                short8 b01 = *(const short8*)(pB01 + off);
                short8 b11 = *(const short8*)(pB11 + off);
                bf16x8 v1;
#pragma unroll
                for (int j = 0; j < 8; ++j) {
                    float f = w00B * tof(b00[j]);
                    f = fmaf(w10B, tof(b10[j]), f);
                    f = fmaf(w01B, tof(b01[j]), f);
                    f = fmaf(w11B, tof(b11[j]), f);
                    v1[j] = (__bf16)f;
                }
                *(bf16x8*)(sb1 + 2 * ((cg * 8) ^ swB)) = v1;
            }
        }
    } else {
        const float* hmb = heatmap + (size_t)bsel * CHM * HW * HW;
        auto dofetch = [&](int c, float& a0, float& a1) {
            const float* pl = hmb + c * (HW * HW);
            a0 = fmaf(w00A, pl[o00A], fmaf(w10A, pl[o10A], fmaf(w01A, pl[o01A], w11A * pl[o11A])));
            a1 = fmaf(w00B, pl[o00B], fmaf(w10B, pl[o10B], fmaf(w01B, pl[o01B], w11B * pl[o11B])));
        };
        for (int cg = 0; cg < 7; ++cg) {
            bf16x8 v0, v1;
#pragma unroll
            for (int j = 0; j < 8; ++j) {
                float a0, a1; dofetch(cg * 8 + j, a0, a1);
                v0[j] = (__bf16)a0; v1[j] = (__bf16)a1;
            }
            int so = cg * 8;
            *(bf16x8*)(sb0 + 2 * (so ^ swA)) = v0;
            if (pv1) *(bf16x8*)(sb1 + 2 * (so ^ swB)) = v1;
        }
        {
            bf16x8 v0, v1;
#pragma unroll
            for (int j = 0; j < 6; ++j) {
                float a0, a1; dofetch(56 + j, a0, a1);
                v0[j] = (__bf16)a0; v1[j] = (__bf16)a1;
            }
            v0[6] = (__bf16)0.f; v0[7] = (__bf16)0.f;
            v1[6] = (__bf16)0.f; v1[7] = (__bf16)0.f;
            *(bf16x8*)(sb0 + 2 * (56 ^ swA)) = v0;
            if (pv1) *(bf16x8*)(sb1 + 2 * (56 ^ swB)) = v1;
        }
    }
    __syncthreads();

    // ---- MFMA m-loop: each wave owns 16 output channels (n-tile), loops m-tiles ----
    float bia = bias[wv * 16 + col];
    float ssum = 0.f, ssq = 0.f;
    int mA = col;                                 // A-operand row = lane&15
    int lim = nr * 38 - 1;
    int nt = (nr * 38 + 15) >> 4;                 // 19 or 15
    __bf16* cobase = conv_out + ((size_t)img * Pp + oy0 * 38) * 64 + (wv * 16 + col);
    int cb = chunk << 4;

    for (int tt = 0; tt < nt; tt += 2) {
        f32x4 acc0 = {0.f, 0.f, 0.f, 0.f}, acc1 = {0.f, 0.f, 0.f, 0.f};
        bool has1 = (tt + 1) < nt;
        int p0 = tt * 16 + mA;       p0 = p0 > lim ? lim : p0;
        int p1 = (tt + 1) * 16 + mA; p1 = p1 > lim ? lim : p1;
        int oyl0 = p0 / 38, ox0 = p0 - oyl0 * 38;
        int oyl1 = p1 / 38, ox1 = p1 - oyl1 * 38;
        int rb0 = oyl0 * 5120, rb1 = oyl1 * 5120;
        int xb0[3], xs0[3], xb1[3], xs1[3];
#pragma unroll
        for (int kk = 0; kk < 3; ++kk) {
            xb0[kk] = (ox0 + kk) * 128; xs0[kk] = ((ox0 + kk) & 7) << 4;
            xb1[kk] = (ox1 + kk) * 128; xs1[kk] = ((ox1 + kk) & 7) << 4;
        }
#pragma unroll
        for (int s = 0; s < 18; ++s) {
            const int tap = s >> 1;
            const int ky = tap / 3, kx = tap % 3;
            const int hb2 = (s & 1) << 6;
            int a0 = rb0 + ky * 5120 + xb0[kx] + ((hb2 | cb) ^ xs0[kx]);
            short8 av0 = *(const short8*)(smem + a0);
            acc0 = __builtin_amdgcn_mfma_f32_16x16x32_bf16(bc(av0), bc(bfr[s]), acc0, 0, 0, 0);
            if (has1) {
                int a1 = rb1 + ky * 5120 + xb1[kx] + ((hb2 | cb) ^ xs1[kx]);
                short8 av1 = *(const short8*)(smem + a1);
                acc1 = __builtin_amdgcn_mfma_f32_16x16x32_bf16(bc(av1), bc(bfr[s]), acc1, 0, 0, 0);
            }
        }
        // epilogue: C row = chunk*4 + reg, col = lane&15 (channel)
#pragma unroll
        for (int r2 = 0; r2 < 4; ++r2) {
            int pl = tt * 16 + chunk * 4 + r2;
            if (pl <= lim) {
                float v = acc0[r2] + bia;
                cobase[(size_t)pl * 64] = (__bf16)v;
                ssum += v; ssq = fmaf(v, v, ssq);
            }
        }
        if (has1) {
#pragma unroll
            for (int r2 = 0; r2 < 4; ++r2) {
                int pl = (tt + 1) * 16 + chunk * 4 + r2;
                if (pl <= lim) {
                    float v = acc1[r2] + bia;
                    cobase[(size_t)pl * 64] = (__bf16)v;
                    ssum += v; ssq = fmaf(v, v, ssq);
                }
            }
        }
    }

    // cross-lane: sum lanes {l, l^16, l^32, l^48} (same output col)
    ssum += __shfl_xor(ssum, 16); ssum += __shfl_xor(ssum, 32);
    ssq  += __shfl_xor(ssq, 16);  ssq  += __shfl_xor(ssq, 32);
    if (lane < 16) {
        partials[((size_t)bid * 64 + wv * 16 + lane) * 2]     = ssum;
        partials[((size_t)bid * 64 + wv * 16 + lane) * 2 + 1] = ssq;
    }
}

// ============ K3b: reduce per-block sums -> BN a,b per channel ============
__global__ void k_stats(const float* __restrict__ partials, const float* __restrict__ gamma,
                        const float* __restrict__ beta, float* __restrict__ ab) {
    __shared__ float red[256][2];
    int oc = blockIdx.x, t = threadIdx.x;
    float S = 0.f, S2 = 0.f;
    for (int j = t; j < NBLK2; j += 256) {
        S  += partials[((size_t)j * 64 + oc) * 2];
        S2 += partials[((size_t)j * 64 + oc) * 2 + 1];
    }
    red[t][0] = S; red[t][1] = S2;
    __syncthreads();
    for (int off = 128; off >= 1; off >>= 1) {
        if (t < off) { red[t][0] += red[t + off][0]; red[t][1] += red[t + off][1]; }
        __syncthreads();
    }
    if (t == 0) {
        float cnt = (float)NIMG * (float)Pp;
        float mu  = red[0][0] / cnt;
        float var = red[0][1] / cnt - mu * mu;
        float a = gamma[oc] * rsqrtf(var + 1e-5f);
        ab[oc * 2] = a;
        ab[oc * 2 + 1] = beta[oc] - mu * a;
    }
}

// ============ K4: BN+ReLU+pool from conv_out + final 1x1 ============
__global__ __launch_bounds__(512) void k_pool_reload(
    const __bf16* __restrict__ conv_out, const float* __restrict__ ab,
    const float* __restrict__ w2, const float* __restrict__ b2, float* __restrict__ out) {
    __shared__ float red[8][64], pooled[64], red2[2][64];
    int img = blockIdx.x, t = threadIdx.x;
    int oc = t & 63, pc = t >> 6;
    float a = ab[oc * 2], bb = ab[oc * 2 + 1];
    float pp = 0.f;
    const __bf16* src = conv_out + (size_t)img * Pp * 64;
    for (int p = pc; p < Pp; p += 8) {
        float v = (float)src[(size_t)p * 64 + oc];
        pp += fmaxf(fmaf(a, v, bb), 0.f);
    }
    red[pc][oc] = pp;
    __syncthreads();
    if (t < 64) {
        float s = 0.f;
#pragma unroll
        for (int j = 0; j < 8; ++j) s += red[j][t];
        pooled[t] = s * (1.f / (float)Pp);
    }
    __syncthreads();
    if (t < 128) {
        int j = t >> 6, c = t & 63;
        red2[j][c] = pooled[c] * w2[j * 64 + c];
    }
    __syncthreads();
    if (t < 2) {
        float s = b2[t];
        for (int c = 0; c < 64; ++c) s += red2[t][c];
        out[img * 2 + t] = s;
    }
}

// ============ host ============
extern "C" void kernel_launch(void* const* d_in, const int* in_sizes, int n_in,
                              void* d_out, int out_size, void* d_ws, size_t ws_size,
                              hipStream_t stream) {
    const float* q   = (const float*)d_in[0];
    const float* hm  = (const float*)d_in[1];
    const float* w1  = (const float*)d_in[2];
    const float* b1  = (const float*)d_in[3];
    const float* w2  = (const float*)d_in[4];
    const float* b2  = (const float*)d_in[5];
    const float* w3  = (const float*)d_in[6];
    const float* b3  = (const float*)d_in[7];
    const float* cw  = (const float*)d_in[8];
    const float* cb  = (const float*)d_in[9];
    const float* gam = (const float*)d_in[10];
    const float* bet = (const float*)d_in[11];
    const float* c2w = (const float*)d_in[12];
    const float* c2b = (const float*)d_in[13];
    float* out = (float*)d_out;
    char* ws = (char*)d_ws;

    float* theta    = (float*)(ws + OFF_THETA);
    __bf16* wb      = (__bf16*)(ws + OFF_WB);
    float* partials = (float*)(ws + OFF_PART);
    float* ab       = (float*)(ws + OFF_AB);

    bool hmt = ws_size >= NEED_HMT;
    __bf16* hmT      = (__bf16*)(ws + OFF_HMT);
    __bf16* conv_out = (__bf16*)(ws + (hmt ? OFF_CONV_H : OFF_CONV_L));

    k_theta<<<NIMG, 64, 0, stream>>>(q, w1, b1, w2, b2, w3, b3, theta);
    k_wcvt2<<<(64 * KP + 255) / 256, 256, 0, stream>>>(cw, wb);
    if (hmt) {
        k_hmT<<<Bc * HW, 192, 0, stream>>>(hm, hmT);
        k_conv2<1><<<NBLK2, 256, 0, stream>>>(hm, hmT, theta, wb, cb, partials, conv_out);
    } else {
        k_conv2<0><<<NBLK2, 256, 0, stream>>>(hm, hmT, theta, wb, cb, partials, conv_out);
    }
    k_stats<<<64, 256, 0, stream>>>(partials, gam, bet, ab);
    k_pool_reload<<<NIMG, 512, 0, stream>>>(conv_out, ab, c2w, c2b, out);
}

// Round 5
// 232.770 us; speedup vs baseline: 11.3276x; 1.0565x over previous
//
#include <hip/hip_runtime.h>

// ---------------- problem constants ----------------
constexpr int Bc = 2, Nc = 256, CHM = 62;
constexpr int HW = 180;            // heatmap H=W
constexpr int OH = 38;             // conv out H=W
constexpr int Pp = OH * OH;        // 1444 positions
constexpr int NIMG = Bc * Nc;      // 512 images (n-major: img = n*B + b)
constexpr int R2 = 8;              // output rows per conv block
constexpr int NRB2 = 5;            // row-blocks per image (8,8,8,8,6)
constexpr int NBLK2 = NIMG * NRB2; // 2560
constexpr int KP = 576;            // padded K = 9 taps * 64 ch

// ---------------- ws layout (bytes) ----------------
constexpr size_t OFF_THETA = 0;            // 512*6*4        = 12,288
constexpr size_t OFF_WB    = 16384;        // 64*576*2 bf16  = 73,728
constexpr size_t OFF_AB    = 90112;        // 64*2*4         = 512
// hmT path:
constexpr size_t OFF_HMT    = 131072;      // 2*180*180*64*2 = 8,294,400 -> 8,425,472
constexpr size_t OFF_PART_H = 8425472;     // 2560*64*2*4    = 1,310,720 -> 9,736,192
constexpr size_t OFF_CONV_H = 9736192;     // + 94,633,984   -> 104,370,176
constexpr size_t NEED_HMT   = 104370176;   // proven available (round 4 ran this path)
// legacy path (no hmT):
constexpr size_t OFF_PART_L = 131072;
constexpr size_t OFF_CONV_L = 1441792;     // + 94,633,984 -> 96,075,776

typedef __attribute__((ext_vector_type(8))) short  short8;
typedef __attribute__((ext_vector_type(8))) __bf16 bf16x8;
typedef __attribute__((ext_vector_type(4))) float  f32x4;

__device__ __forceinline__ bf16x8 bc(short8 v) { return __builtin_bit_cast(bf16x8, v); }
__device__ __forceinline__ float tof(short s) {
    return __uint_as_float(((unsigned)(unsigned short)s) << 16);
}

// ============ K1: fc_loc MLP -> theta[img][6], img = n*B + b ============
__global__ void k_theta(const float* __restrict__ q,
                        const float* __restrict__ w1, const float* __restrict__ b1,
                        const float* __restrict__ w2, const float* __restrict__ b2,
                        const float* __restrict__ w3, const float* __restrict__ b3,
                        float* __restrict__ theta) {
    __shared__ float qv[256], h1[64], h2[64];
    int qi = blockIdx.x;           // = b*N + n
    int t  = threadIdx.x;          // 64 threads
    int b = qi >> 8, n = qi & 255;
    const float* qrow = q + qi * 256;
    for (int i = t; i < 256; i += 64) qv[i] = qrow[i];
    __syncthreads();
    float s = b1[t];
    const float* wr = w1 + t * 256;
    for (int i = 0; i < 256; ++i) s = fmaf(qv[i], wr[i], s);
    h1[t] = fmaxf(s, 0.f);
    __syncthreads();
    s = b2[t]; wr = w2 + t * 64;
    for (int i = 0; i < 64; ++i) s = fmaf(h1[i], wr[i], s);
    h2[t] = fmaxf(s, 0.f);
    __syncthreads();
    if (t < 6) {
        s = b3[t]; wr = w3 + t * 64;
        for (int i = 0; i < 64; ++i) s = fmaf(h2[i], wr[i], s);
        theta[(n * Bc + b) * 6 + t] = s;
    }
}

// ============ K2: conv1 weights fp32 [oc][ic][ky][kx] -> bf16 wb[n][k], k=(tap*64+ic) ============
__global__ void k_wcvt2(const float* __restrict__ w, __bf16* __restrict__ wb) {
    int idx = blockIdx.x * 256 + threadIdx.x;      // over 64*576
    if (idx < 64 * KP) {
        int n = idx / KP, k = idx - n * KP;
        int tap = k >> 6, ic = k & 63;
        float v = (ic < CHM) ? w[(n * CHM + ic) * 9 + tap] : 0.f;
        wb[idx] = (__bf16)v;
    }
}

// ============ K2b: heatmap [2][62][180][180] f32 -> hmT [2][180*180][64] bf16 ============
__global__ __launch_bounds__(192) void k_hmT(const float* __restrict__ hm, __bf16* __restrict__ hmT) {
    int by = blockIdx.x;           // b*180 + y
    int b = by / HW, y = by - b * HW;
    int x = threadIdx.x;
    if (x < HW) {
        const float* src = hm + (size_t)b * CHM * (HW * HW) + y * HW + x;
        __bf16* dst = hmT + ((size_t)(b * (HW * HW) + y * HW + x)) * 64;
#pragma unroll
        for (int g = 0; g < 8; ++g) {
            bf16x8 v;
#pragma unroll
            for (int j = 0; j < 8; ++j) {
                int c = g * 8 + j;
                v[j] = (c < CHM) ? (__bf16)src[(size_t)c * (HW * HW)] : (__bf16)0.f;
            }
            *(bf16x8*)(dst + g * 8) = v;
        }
    }
}

// ============ K3: fused sample + MFMA implicit-GEMM conv ============
// strip LDS: [rx<=10*40][ic:64] bf16, 16B-granular swizzle: elem ^= (x&7)<<3
// wave (q,h): q = m-tile parity, h = oc-half; 2 B n-tiles in regs, 2 MFMA per A-read
#define PREP(S, PIDX, VLD) \
    int o00##S, o10##S, o01##S, o11##S, eb##S, sw##S; \
    float w00##S, w10##S, w01##S, w11##S; \
    { int p = (PIDX); \
      int r = p / 40, x = p - r * 40; \
      float gx = (2 * x + 1) * 0.025f - 1.f; \
      float gy = (2 * (oy0 + r) + 1) * 0.025f - 1.f; \
      float X = fmaf(t00, gx, fmaf(t01, gy, t02)); \
      float Y = fmaf(t10, gx, fmaf(t11, gy, t12)); \
      float ix = fmaf(X, 90.f, 89.5f), iy = fmaf(Y, 90.f, 89.5f); \
      float xf = floorf(ix), yf = floorf(iy); \
      float fx = ix - xf, fy = iy - yf; \
      int x0 = (int)xf, y0 = (int)yf; \
      bool xi0 = (unsigned)x0 < (unsigned)HW, xi1 = (unsigned)(x0 + 1) < (unsigned)HW; \
      bool yi0 = (unsigned)y0 < (unsigned)HW, yi1 = (unsigned)(y0 + 1) < (unsigned)HW; \
      float vm = (VLD) ? 1.f : 0.f; \
      w00##S = (xi0 & yi0) ? (1.f - fx) * (1.f - fy) * vm : 0.f; \
      w10##S = (xi1 & yi0) ? fx * (1.f - fy) * vm : 0.f; \
      w01##S = (xi0 & yi1) ? (1.f - fx) * fy * vm : 0.f; \
      w11##S = (xi1 & yi1) ? fx * fy * vm : 0.f; \
      o00##S = (xi0 & yi0) ? y0 * HW + x0 : 0; \
      o10##S = (xi1 & yi0) ? y0 * HW + x0 + 1 : 0; \
      o01##S = (xi0 & yi1) ? (y0 + 1) * HW + x0 : 0; \
      o11##S = (xi1 & yi1) ? (y0 + 1) * HW + x0 + 1 : 0; \
      eb##S = p << 6; sw##S = (x & 7) << 3; \
    }

template<int HMT>
__global__ __launch_bounds__(256, 3) void k_conv2(
    const float* __restrict__ heatmap, const __bf16* __restrict__ hmT,
    const float* __restrict__ theta, const __bf16* __restrict__ wb,
    const float* __restrict__ bias, float* __restrict__ partials,
    __bf16* __restrict__ conv_out) {
    __shared__ char smem[52224];                 // 10*40*64*2 strip + 1KB red

    int bid = blockIdx.x;
    int n = bid & 255, bsel = (bid >> 8) & 1, ry = bid >> 9;
    int img = n * Bc + bsel;
    int oy0 = ry * R2;
    int nr  = (ry == NRB2 - 1) ? 6 : 8;          // output rows this block
    int t = threadIdx.x;
    int lane = t & 63, wv = t >> 6;
    int col = lane & 15, chunk = lane >> 4;
    int qw = wv >> 1, h = wv & 1;                // position-parity, oc-half

    // ---- sampling ----
    const float* th = theta + img * 6;
    float t00 = th[0], t01 = th[1], t02 = th[2];
    float t10 = th[3], t11 = th[4], t12 = th[5];
    int rows = nr + 2, npos = rows * 40;

    bool pv1 = (t + 256) < npos;
    PREP(A, t, true)
    PREP(B, t + 256, pv1)
    char* sb0 = smem + 2 * ebA;
    char* sb1 = smem + 2 * ebB;

    if constexpr (HMT) {
        const char* hb = (const char*)(hmT + (size_t)bsel * ((size_t)HW * HW * 64));
        const char* pA00 = hb + (size_t)o00A * 128;
        const char* pA10 = hb + (size_t)o10A * 128;
        const char* pA01 = hb + (size_t)o01A * 128;
        const char* pA11 = hb + (size_t)o11A * 128;
        const char* pB00 = hb + (size_t)o00B * 128;
        const char* pB10 = hb + (size_t)o10B * 128;
        const char* pB01 = hb + (size_t)o01B * 128;
        const char* pB11 = hb + (size_t)o11B * 128;
#pragma unroll
        for (int cg = 0; cg < 8; ++cg) {
            int off = cg * 16;
            short8 a00 = *(const short8*)(pA00 + off);
            short8 a10 = *(const short8*)(pA10 + off);
            short8 a01 = *(const short8*)(pA01 + off);
            short8 a11 = *(const short8*)(pA11 + off);
            bf16x8 v0;
#pragma unroll
            for (int j = 0; j < 8; ++j) {
                float f = w00A * tof(a00[j]);
                f = fmaf(w10A, tof(a10[j]), f);
                f = fmaf(w01A, tof(a01[j]), f);
                f = fmaf(w11A, tof(a11[j]), f);
                v0[j] = (__bf16)f;
            }
            *(bf16x8*)(sb0 + 2 * ((cg * 8) ^ swA)) = v0;
            if (pv1) {
                short8 b00 = *(const short8*)(pB00 + off);
                short8 b10 = *(const short8*)(pB10 + off);
                short8 b01 = *(const short8*)(pB01 + off);
                short8 b11 = *(const short8*)(pB11 + off);
                bf16x8 v1;
#pragma unroll
                for (int j = 0; j < 8; ++j) {
                    float f = w00B * tof(b00[j]);
                    f = fmaf(w10B, tof(b10[j]), f);
                    f = fmaf(w01B, tof(b01[j]), f);
                    f = fmaf(w11B, tof(b11[j]), f);
                    v1[j] = (__bf16)f;
                }
                *(bf16x8*)(sb1 + 2 * ((cg * 8) ^ swB)) = v1;
            }
        }
    } else {
        const float* hmb = heatmap + (size_t)bsel * CHM * HW * HW;
        auto dofetch = [&](int c, float& a0, float& a1) {
            const float* pl = hmb + c * (HW * HW);
            a0 = fmaf(w00A, pl[o00A], fmaf(w10A, pl[o10A], fmaf(w01A, pl[o01A], w11A * pl[o11A])));
            a1 = fmaf(w00B, pl[o00B], fmaf(w10B, pl[o10B], fmaf(w01B, pl[o01B], w11B * pl[o11B])));
        };
        for (int cg = 0; cg < 7; ++cg) {
            bf16x8 v0, v1;
#pragma unroll
            for (int j = 0; j < 8; ++j) {
                float a0, a1; dofetch(cg * 8 + j, a0, a1);
                v0[j] = (__bf16)a0; v1[j] = (__bf16)a1;
            }
            int so = cg * 8;
            *(bf16x8*)(sb0 + 2 * (so ^ swA)) = v0;
            if (pv1) *(bf16x8*)(sb1 + 2 * (so ^ swB)) = v1;
        }
        {
            bf16x8 v0, v1;
#pragma unroll
            for (int j = 0; j < 6; ++j) {
                float a0, a1; dofetch(56 + j, a0, a1);
                v0[j] = (__bf16)a0; v1[j] = (__bf16)a1;
            }
            v0[6] = (__bf16)0.f; v0[7] = (__bf16)0.f;
            v1[6] = (__bf16)0.f; v1[7] = (__bf16)0.f;
            *(bf16x8*)(sb0 + 2 * (56 ^ swA)) = v0;
            if (pv1) *(bf16x8*)(sb1 + 2 * (56 ^ swB)) = v1;
        }
    }

    // ---- B fragments: 2 n-tiles (32 oc) per wave, loaded after sampling ----
    short8 bfr0[18], bfr1[18];
    {
        int nn0 = h * 32 + col;
        const char* wp0 = (const char*)wb + (size_t)nn0 * (KP * 2) + chunk * 16;
        const char* wp1 = wp0 + 16 * (KP * 2);
#pragma unroll
        for (int s = 0; s < 18; ++s) {
            bfr0[s] = *(const short8*)(wp0 + s * 64);
            bfr1[s] = *(const short8*)(wp1 + s * 64);
        }
    }
    __syncthreads();

    // ---- MFMA m-loop: wave (qw,h) does m-tiles tt=qw,qw+2,..; 32 oc each ----
    float bia0 = bias[h * 32 + col], bia1 = bias[h * 32 + 16 + col];
    float ssum0 = 0.f, ssq0 = 0.f, ssum1 = 0.f, ssq1 = 0.f;
    int mA = col;                                 // A-operand row = lane&15
    int lim = nr * 38 - 1;
    int nt = (nr * 38 + 15) >> 4;                 // 19 or 15
    __bf16* cobase0 = conv_out + ((size_t)img * Pp + oy0 * 38) * 64 + (h * 32 + col);
    __bf16* cobase1 = cobase0 + 16;
    int cb = chunk << 4;

    for (int tt = qw; tt < nt; tt += 2) {
        f32x4 acc0 = {0.f, 0.f, 0.f, 0.f}, acc1 = {0.f, 0.f, 0.f, 0.f};
        int p0 = tt * 16 + mA; p0 = p0 > lim ? lim : p0;
        int oyl = p0 / 38, ox = p0 - oyl * 38;
        int rb = oyl * 5120;
        int xb[3], xs[3];
#pragma unroll
        for (int kk = 0; kk < 3; ++kk) {
            xb[kk] = (ox + kk) * 128; xs[kk] = ((ox + kk) & 7) << 4;
        }
#pragma unroll
        for (int s = 0; s < 18; ++s) {
            const int tap = s >> 1;
            const int ky = tap / 3, kx = tap % 3;
            const int hb2 = (s & 1) << 6;
            int a0 = rb + ky * 5120 + xb[kx] + ((hb2 | cb) ^ xs[kx]);
            short8 av = *(const short8*)(smem + a0);
            acc0 = __builtin_amdgcn_mfma_f32_16x16x32_bf16(bc(av), bc(bfr0[s]), acc0, 0, 0, 0);
            acc1 = __builtin_amdgcn_mfma_f32_16x16x32_bf16(bc(av), bc(bfr1[s]), acc1, 0, 0, 0);
        }
        // epilogue: C row = chunk*4 + reg (position), col = lane&15 (oc within n-tile)
#pragma unroll
        for (int r2 = 0; r2 < 4; ++r2) {
            int pl = tt * 16 + chunk * 4 + r2;
            if (pl <= lim) {
                float v0 = acc0[r2] + bia0;
                cobase0[(size_t)pl * 64] = (__bf16)v0;
                ssum0 += v0; ssq0 = fmaf(v0, v0, ssq0);
                float v1 = acc1[r2] + bia1;
                cobase1[(size_t)pl * 64] = (__bf16)v1;
                ssum1 += v1; ssq1 = fmaf(v1, v1, ssq1);
            }
        }
    }

    // cross-lane: sum lanes {l, l^16, l^32, l^48} (same oc col)
    ssum0 += __shfl_xor(ssum0, 16); ssum0 += __shfl_xor(ssum0, 32);
    ssq0  += __shfl_xor(ssq0, 16);  ssq0  += __shfl_xor(ssq0, 32);
    ssum1 += __shfl_xor(ssum1, 16); ssum1 += __shfl_xor(ssum1, 32);
    ssq1  += __shfl_xor(ssq1, 16);  ssq1  += __shfl_xor(ssq1, 32);

    // combine the two q-waves via LDS red region [2][64][2] @ 51200
    float* redq = (float*)(smem + 51200);
    __syncthreads();
    if (lane < 16) {
        int o0 = (qw * 64 + h * 32 + lane) * 2;
        redq[o0] = ssum0;          redq[o0 + 1] = ssq0;
        redq[o0 + 32] = ssum1;     redq[o0 + 33] = ssq1;   // +16 oc -> +32 floats
    }
    __syncthreads();
    if (t < 64) {
        float S  = redq[t * 2]     + redq[(64 + t) * 2];
        float S2 = redq[t * 2 + 1] + redq[(64 + t) * 2 + 1];
        partials[((size_t)bid * 64 + t) * 2]     = S;
        partials[((size_t)bid * 64 + t) * 2 + 1] = S2;
    }
}

// ============ K3b: reduce per-block sums -> BN a,b per channel ============
__global__ void k_stats(const float* __restrict__ partials, const float* __restrict__ gamma,
                        const float* __restrict__ beta, float* __restrict__ ab) {
    __shared__ float red[256][2];
    int oc = blockIdx.x, t = threadIdx.x;
    float S = 0.f, S2 = 0.f;
    for (int j = t; j < NBLK2; j += 256) {
        S  += partials[((size_t)j * 64 + oc) * 2];
        S2 += partials[((size_t)j * 64 + oc) * 2 + 1];
    }
    red[t][0] = S; red[t][1] = S2;
    __syncthreads();
    for (int off = 128; off >= 1; off >>= 1) {
        if (t < off) { red[t][0] += red[t + off][0]; red[t][1] += red[t + off][1]; }
        __syncthreads();
    }
    if (t == 0) {
        float cnt = (float)NIMG * (float)Pp;
        float mu  = red[0][0] / cnt;
        float var = red[0][1] / cnt - mu * mu;
        float a = gamma[oc] * rsqrtf(var + 1e-5f);
        ab[oc * 2] = a;
        ab[oc * 2 + 1] = beta[oc] - mu * a;
    }
}

// ============ K4: BN+ReLU+pool from conv_out + final 1x1 (vectorized) ============
__global__ __launch_bounds__(512) void k_pool_reload(
    const __bf16* __restrict__ conv_out, const float* __restrict__ ab,
    const float* __restrict__ w2, const float* __restrict__ b2, float* __restrict__ out) {
    __shared__ float red[64][65];
    __shared__ float pooled[64], red2[2][64];
    int img = blockIdx.x, t = threadIdx.x;
    int pidx = t >> 3, ocg = t & 7;
    float a[8], bb[8];
#pragma unroll
    for (int j = 0; j < 8; ++j) {
        a[j]  = ab[(ocg * 8 + j) * 2];
        bb[j] = ab[(ocg * 8 + j) * 2 + 1];
    }
    float s[8];
#pragma unroll
    for (int j = 0; j < 8; ++j) s[j] = 0.f;
    const __bf16* src = conv_out + (size_t)img * Pp * 64 + ocg * 8;
    for (int p = pidx; p < Pp; p += 64) {
        short8 v = *(const short8*)(src + (size_t)p * 64);
#pragma unroll
        for (int j = 0; j < 8; ++j)
            s[j] += fmaxf(fmaf(a[j], tof(v[j]), bb[j]), 0.f);
    }
#pragma unroll
    for (int j = 0; j < 8; ++j) red[pidx][ocg * 8 + j] = s[j];
    __syncthreads();
    if (t < 64) {
        float S = 0.f;
        for (int p = 0; p < 64; ++p) S += red[p][t];
        pooled[t] = S * (1.f / (float)Pp);
    }
    __syncthreads();
    if (t < 128) {
        int j = t >> 6, c = t & 63;
        red2[j][c] = pooled[c] * w2[j * 64 + c];
    }
    __syncthreads();
    if (t < 2) {
        float ss = b2[t];
        for (int c = 0; c < 64; ++c) ss += red2[t][c];
        out[img * 2 + t] = ss;
    }
}

// ============ host ============
extern "C" void kernel_launch(void* const* d_in, const int* in_sizes, int n_in,
                              void* d_out, int out_size, void* d_ws, size_t ws_size,
                              hipStream_t stream) {
    const float* q   = (const float*)d_in[0];
    const float* hm  = (const float*)d_in[1];
    const float* w1  = (const float*)d_in[2];
    const float* b1  = (const float*)d_in[3];
    const float* w2  = (const float*)d_in[4];
    const float* b2  = (const float*)d_in[5];
    const float* w3  = (const float*)d_in[6];
    const float* b3  = (const float*)d_in[7];
    const float* cw  = (const float*)d_in[8];
    const float* cb  = (const float*)d_in[9];
    const float* gam = (const float*)d_in[10];
    const float* bet = (const float*)d_in[11];
    const float* c2w = (const float*)d_in[12];
    const float* c2b = (const float*)d_in[13];
    float* out = (float*)d_out;
    char* ws = (char*)d_ws;

    float* theta = (float*)(ws + OFF_THETA);
    __bf16* wb   = (__bf16*)(ws + OFF_WB);
    float* ab    = (float*)(ws + OFF_AB);

    bool hmt = ws_size >= NEED_HMT;
    __bf16* hmT      = (__bf16*)(ws + OFF_HMT);
    float* partials  = (float*)(ws + (hmt ? OFF_PART_H : OFF_PART_L));
    __bf16* conv_out = (__bf16*)(ws + (hmt ? OFF_CONV_H : OFF_CONV_L));

    k_theta<<<NIMG, 64, 0, stream>>>(q, w1, b1, w2, b2, w3, b3, theta);
    k_wcvt2<<<(64 * KP + 255) / 256, 256, 0, stream>>>(cw, wb);
    if (hmt) {
        k_hmT<<<Bc * HW, 192, 0, stream>>>(hm, hmT);
        k_conv2<1><<<NBLK2, 256, 0, stream>>>(hm, hmT, theta, wb, cb, partials, conv_out);
    } else {
        k_conv2<0><<<NBLK2, 256, 0, stream>>>(hm, hmT, theta, wb, cb, partials, conv_out);
    }
    k_stats<<<64, 256, 0, stream>>>(partials, gam, bet, ab);
    k_pool_reload<<<NIMG, 512, 0, stream>>>(conv_out, ab, c2w, c2b, out);
}

// Round 6
// 211.466 us; speedup vs baseline: 12.4688x; 1.1007x over previous
//
#include <hip/hip_runtime.h>

// ---------------- problem constants ----------------
constexpr int Bc = 2, Nc = 256, CHM = 62;
constexpr int HW = 180;            // heatmap H=W
constexpr int OH = 38;             // conv out H=W
constexpr int Pp = OH * OH;        // 1444 positions
constexpr int NIMG = Bc * Nc;      // 512 images (n-major: img = n*B + b)
constexpr int R2 = 8;              // output rows per conv block
constexpr int NRB2 = 5;            // row-blocks per image (8,8,8,8,6)
constexpr int NBLK2 = NIMG * NRB2; // 2560
constexpr int KP = 576;            // padded K = 9 taps * 64 ch

// ---------------- ws layout (bytes) ----------------
constexpr size_t OFF_THETA = 0;            // 512*6*4        = 12,288
constexpr size_t OFF_WB    = 16384;        // 64*576*2 bf16  = 73,728
constexpr size_t OFF_AB    = 90112;        // 64*2*4         = 512
// hmT path:
constexpr size_t OFF_HMT    = 131072;      // 2*180*180*64*2 = 8,294,400 -> 8,425,472
constexpr size_t OFF_PART_H = 8425472;     // 2560*64*2*4    = 1,310,720 -> 9,736,192
constexpr size_t OFF_CONV_H = 9736192;     // + 94,633,984   -> 104,370,176
constexpr size_t NEED_HMT   = 104370176;   // proven available (rounds 4/5 ran this path)
// legacy path (no hmT):
constexpr size_t OFF_PART_L = 131072;
constexpr size_t OFF_CONV_L = 1441792;     // + 94,633,984 -> 96,075,776

typedef __attribute__((ext_vector_type(8))) short  short8;
typedef __attribute__((ext_vector_type(8))) __bf16 bf16x8;
typedef __attribute__((ext_vector_type(4))) float  f32x4;

__device__ __forceinline__ bf16x8 bc(short8 v) { return __builtin_bit_cast(bf16x8, v); }
__device__ __forceinline__ float tof(short s) {
    return __uint_as_float(((unsigned)(unsigned short)s) << 16);
}

// ============ K1: fc_loc MLP -> theta[img][6], img = n*B + b ============
__global__ void k_theta(const float* __restrict__ q,
                        const float* __restrict__ w1, const float* __restrict__ b1,
                        const float* __restrict__ w2, const float* __restrict__ b2,
                        const float* __restrict__ w3, const float* __restrict__ b3,
                        float* __restrict__ theta) {
    __shared__ float qv[256], h1[64], h2[64];
    int qi = blockIdx.x;           // = b*N + n
    int t  = threadIdx.x;          // 64 threads
    int b = qi >> 8, n = qi & 255;
    const float* qrow = q + qi * 256;
    for (int i = t; i < 256; i += 64) qv[i] = qrow[i];
    __syncthreads();
    float s = b1[t];
    const float* wr = w1 + t * 256;
    for (int i = 0; i < 256; ++i) s = fmaf(qv[i], wr[i], s);
    h1[t] = fmaxf(s, 0.f);
    __syncthreads();
    s = b2[t]; wr = w2 + t * 64;
    for (int i = 0; i < 64; ++i) s = fmaf(h1[i], wr[i], s);
    h2[t] = fmaxf(s, 0.f);
    __syncthreads();
    if (t < 6) {
        s = b3[t]; wr = w3 + t * 64;
        for (int i = 0; i < 64; ++i) s = fmaf(h2[i], wr[i], s);
        theta[(n * Bc + b) * 6 + t] = s;
    }
}

// ============ K2: conv1 weights fp32 [oc][ic][ky][kx] -> bf16 wb[n][k], k=(tap*64+ic) ============
__global__ void k_wcvt2(const float* __restrict__ w, __bf16* __restrict__ wb) {
    int idx = blockIdx.x * 256 + threadIdx.x;      // over 64*576
    if (idx < 64 * KP) {
        int n = idx / KP, k = idx - n * KP;
        int tap = k >> 6, ic = k & 63;
        float v = (ic < CHM) ? w[(n * CHM + ic) * 9 + tap] : 0.f;
        wb[idx] = (__bf16)v;
    }
}

// ============ K2b: heatmap [2][62][180][180] f32 -> hmT [2][180*180][64] bf16 ============
__global__ __launch_bounds__(192) void k_hmT(const float* __restrict__ hm, __bf16* __restrict__ hmT) {
    int by = blockIdx.x;           // b*180 + y
    int b = by / HW, y = by - b * HW;
    int x = threadIdx.x;
    if (x < HW) {
        const float* src = hm + (size_t)b * CHM * (HW * HW) + y * HW + x;
        __bf16* dst = hmT + ((size_t)(b * (HW * HW) + y * HW + x)) * 64;
#pragma unroll
        for (int g = 0; g < 8; ++g) {
            bf16x8 v;
#pragma unroll
            for (int j = 0; j < 8; ++j) {
                int c = g * 8 + j;
                v[j] = (c < CHM) ? (__bf16)src[(size_t)c * (HW * HW)] : (__bf16)0.f;
            }
            *(bf16x8*)(dst + g * 8) = v;
        }
    }
}

// ============ K3: fused sample + MFMA implicit-GEMM conv ============
// 512 threads = 8 waves = 4 oc-tiles (h) x 2 m-pair-parity (qp).
// strip LDS: [rx<=10*40][ic:64] bf16, 16B-granular swizzle: elem ^= (x&7)<<3
// sampling: 1 position per thread, channel-last hmT gather (dwordx4).
#define PREP(S, PIDX, VLD) \
    int o00##S, o10##S, o01##S, o11##S, eb##S, sw##S; \
    float w00##S, w10##S, w01##S, w11##S; \
    { int p = (PIDX); \
      int r = p / 40, x = p - r * 40; \
      float gx = (2 * x + 1) * 0.025f - 1.f; \
      float gy = (2 * (oy0 + r) + 1) * 0.025f - 1.f; \
      float X = fmaf(t00, gx, fmaf(t01, gy, t02)); \
      float Y = fmaf(t10, gx, fmaf(t11, gy, t12)); \
      float ix = fmaf(X, 90.f, 89.5f), iy = fmaf(Y, 90.f, 89.5f); \
      float xf = floorf(ix), yf = floorf(iy); \
      float fx = ix - xf, fy = iy - yf; \
      int x0 = (int)xf, y0 = (int)yf; \
      bool xi0 = (unsigned)x0 < (unsigned)HW, xi1 = (unsigned)(x0 + 1) < (unsigned)HW; \
      bool yi0 = (unsigned)y0 < (unsigned)HW, yi1 = (unsigned)(y0 + 1) < (unsigned)HW; \
      float vm = (VLD) ? 1.f : 0.f; \
      w00##S = (xi0 & yi0) ? (1.f - fx) * (1.f - fy) * vm : 0.f; \
      w10##S = (xi1 & yi0) ? fx * (1.f - fy) * vm : 0.f; \
      w01##S = (xi0 & yi1) ? (1.f - fx) * fy * vm : 0.f; \
      w11##S = (xi1 & yi1) ? fx * fy * vm : 0.f; \
      o00##S = (xi0 & yi0) ? y0 * HW + x0 : 0; \
      o10##S = (xi1 & yi0) ? y0 * HW + x0 + 1 : 0; \
      o01##S = (xi0 & yi1) ? (y0 + 1) * HW + x0 : 0; \
      o11##S = (xi1 & yi1) ? (y0 + 1) * HW + x0 + 1 : 0; \
      eb##S = p << 6; sw##S = (x & 7) << 3; \
    }

template<int HMT>
__global__ __launch_bounds__(512, 4) void k_conv2(
    const float* __restrict__ heatmap, const __bf16* __restrict__ hmT,
    const float* __restrict__ theta, const __bf16* __restrict__ wb,
    const float* __restrict__ bias, float* __restrict__ partials,
    __bf16* __restrict__ conv_out) {
    __shared__ char smem[52224];                 // 10*40*64*2 strip + 1KB red

    int bid = blockIdx.x;
    int n = bid & 255, bsel = (bid >> 8) & 1, ry = bid >> 9;
    int img = n * Bc + bsel;
    int oy0 = ry * R2;
    int nr  = (ry == NRB2 - 1) ? 6 : 8;          // output rows this block
    int t = threadIdx.x;
    int lane = t & 63, wv = t >> 6;
    int col = lane & 15, chunk = lane >> 4;
    int h = wv & 3, qp = wv >> 2;                // oc-tile, m-pair parity

    // ---- B fragments straight from global into registers (n-tile = h) ----
    short8 bfr[18];
    {
        int nn = h * 16 + col;
        const char* wp = (const char*)wb + (size_t)nn * (KP * 2) + chunk * 16;
#pragma unroll
        for (int s = 0; s < 18; ++s)
            bfr[s] = *(const short8*)(wp + s * 64);
    }

    // ---- sampling: 1 position per thread ----
    const float* th = theta + img * 6;
    float t00 = th[0], t01 = th[1], t02 = th[2];
    float t10 = th[3], t11 = th[4], t12 = th[5];
    int rows = nr + 2, npos = rows * 40;

    if (t < npos) {
        PREP(A, t, true)
        char* sb0 = smem + 2 * ebA;
        if constexpr (HMT) {
            const char* hb = (const char*)(hmT + (size_t)bsel * ((size_t)HW * HW * 64));
            const char* pA00 = hb + (size_t)o00A * 128;
            const char* pA10 = hb + (size_t)o10A * 128;
            const char* pA01 = hb + (size_t)o01A * 128;
            const char* pA11 = hb + (size_t)o11A * 128;
#pragma unroll
            for (int cg = 0; cg < 8; ++cg) {
                int off = cg * 16;
                short8 a00 = *(const short8*)(pA00 + off);
                short8 a10 = *(const short8*)(pA10 + off);
                short8 a01 = *(const short8*)(pA01 + off);
                short8 a11 = *(const short8*)(pA11 + off);
                bf16x8 v0;
#pragma unroll
                for (int j = 0; j < 8; ++j) {
                    float f = w00A * tof(a00[j]);
                    f = fmaf(w10A, tof(a10[j]), f);
                    f = fmaf(w01A, tof(a01[j]), f);
                    f = fmaf(w11A, tof(a11[j]), f);
                    v0[j] = (__bf16)f;
                }
                *(bf16x8*)(sb0 + 2 * ((cg * 8) ^ swA)) = v0;
            }
        } else {
            const float* hmb = heatmap + (size_t)bsel * CHM * HW * HW;
            auto dofetch = [&](int c) -> float {
                const float* pl = hmb + c * (HW * HW);
                return fmaf(w00A, pl[o00A], fmaf(w10A, pl[o10A],
                       fmaf(w01A, pl[o01A], w11A * pl[o11A])));
            };
#pragma unroll
            for (int cg = 0; cg < 8; ++cg) {
                bf16x8 v0;
#pragma unroll
                for (int j = 0; j < 8; ++j) {
                    int c = cg * 8 + j;
                    v0[j] = (c < CHM) ? (__bf16)dofetch(c) : (__bf16)0.f;
                }
                *(bf16x8*)(sb0 + 2 * ((cg * 8) ^ swA)) = v0;
            }
        }
    }
    __syncthreads();

    // ---- MFMA m-loop: wave (h,qp) -> 16 oc, pairs pr=qp,qp+2,.. (2 m-tiles/iter) ----
    float bia = bias[h * 16 + col];
    float ssum = 0.f, ssq = 0.f;
    int mA = col;                                 // A-operand row = lane&15
    int lim = nr * 38 - 1;
    int nt = (nr * 38 + 15) >> 4;                 // 19 or 15
    int npairs = (nt + 1) >> 1;                   // 10 or 8
    __bf16* cobase = conv_out + ((size_t)img * Pp + oy0 * 38) * 64 + (h * 16 + col);
    int cb = chunk << 4;

    for (int pr = qp; pr < npairs; pr += 2) {
        int tt = pr * 2;
        f32x4 acc0 = {0.f, 0.f, 0.f, 0.f}, acc1 = {0.f, 0.f, 0.f, 0.f};
        bool has1 = (tt + 1) < nt;
        int p0 = tt * 16 + mA;       p0 = p0 > lim ? lim : p0;
        int p1 = (tt + 1) * 16 + mA; p1 = p1 > lim ? lim : p1;
        int oyl0 = p0 / 38, ox0 = p0 - oyl0 * 38;
        int oyl1 = p1 / 38, ox1 = p1 - oyl1 * 38;
        int rb0 = oyl0 * 5120, rb1 = oyl1 * 5120;
        int xb0[3], xs0[3], xb1[3], xs1[3];
#pragma unroll
        for (int kk = 0; kk < 3; ++kk) {
            xb0[kk] = (ox0 + kk) * 128; xs0[kk] = ((ox0 + kk) & 7) << 4;
            xb1[kk] = (ox1 + kk) * 128; xs1[kk] = ((ox1 + kk) & 7) << 4;
        }
#pragma unroll
        for (int s = 0; s < 18; ++s) {
            const int tap = s >> 1;
            const int ky = tap / 3, kx = tap % 3;
            const int hb2 = (s & 1) << 6;
            int a0 = rb0 + ky * 5120 + xb0[kx] + ((hb2 | cb) ^ xs0[kx]);
            short8 av0 = *(const short8*)(smem + a0);
            acc0 = __builtin_amdgcn_mfma_f32_16x16x32_bf16(bc(av0), bc(bfr[s]), acc0, 0, 0, 0);
            if (has1) {
                int a1 = rb1 + ky * 5120 + xb1[kx] + ((hb2 | cb) ^ xs1[kx]);
                short8 av1 = *(const short8*)(smem + a1);
                acc1 = __builtin_amdgcn_mfma_f32_16x16x32_bf16(bc(av1), bc(bfr[s]), acc1, 0, 0, 0);
            }
        }
        // epilogue: C row = chunk*4 + reg (position), col = lane&15 (oc)
#pragma unroll
        for (int r2 = 0; r2 < 4; ++r2) {
            int pl = tt * 16 + chunk * 4 + r2;
            if (pl <= lim) {
                float v = acc0[r2] + bia;
                cobase[(size_t)pl * 64] = (__bf16)v;
                ssum += v; ssq = fmaf(v, v, ssq);
            }
        }
        if (has1) {
#pragma unroll
            for (int r2 = 0; r2 < 4; ++r2) {
                int pl = (tt + 1) * 16 + chunk * 4 + r2;
                if (pl <= lim) {
                    float v = acc1[r2] + bia;
                    cobase[(size_t)pl * 64] = (__bf16)v;
                    ssum += v; ssq = fmaf(v, v, ssq);
                }
            }
        }
    }

    // cross-lane: sum lanes {l, l^16, l^32, l^48} (same oc col)
    ssum += __shfl_xor(ssum, 16); ssum += __shfl_xor(ssum, 32);
    ssq  += __shfl_xor(ssq, 16);  ssq  += __shfl_xor(ssq, 32);

    // combine the two qp-waves via LDS red region [2][64][2] @ 51200
    float* redq = (float*)(smem + 51200);
    if (lane < 16) {
        int o = (qp * 64 + h * 16 + lane) * 2;
        redq[o] = ssum; redq[o + 1] = ssq;
    }
    __syncthreads();
    if (t < 64) {
        float S  = redq[t * 2]     + redq[(64 + t) * 2];
        float S2 = redq[t * 2 + 1] + redq[(64 + t) * 2 + 1];
        partials[((size_t)bid * 64 + t) * 2]     = S;
        partials[((size_t)bid * 64 + t) * 2 + 1] = S2;
    }
}

// ============ K3b: reduce per-block sums -> BN a,b per channel ============
__global__ void k_stats(const float* __restrict__ partials, const float* __restrict__ gamma,
                        const float* __restrict__ beta, float* __restrict__ ab) {
    __shared__ float red[256][2];
    int oc = blockIdx.x, t = threadIdx.x;
    float S = 0.f, S2 = 0.f;
    for (int j = t; j < NBLK2; j += 256) {
        S  += partials[((size_t)j * 64 + oc) * 2];
        S2 += partials[((size_t)j * 64 + oc) * 2 + 1];
    }
    red[t][0] = S; red[t][1] = S2;
    __syncthreads();
    for (int off = 128; off >= 1; off >>= 1) {
        if (t < off) { red[t][0] += red[t + off][0]; red[t][1] += red[t + off][1]; }
        __syncthreads();
    }
    if (t == 0) {
        float cnt = (float)NIMG * (float)Pp;
        float mu  = red[0][0] / cnt;
        float var = red[0][1] / cnt - mu * mu;
        float a = gamma[oc] * rsqrtf(var + 1e-5f);
        ab[oc * 2] = a;
        ab[oc * 2 + 1] = beta[oc] - mu * a;
    }
}

// ============ K4: BN+ReLU+pool from conv_out + final 1x1 (vectorized) ============
__global__ __launch_bounds__(512) void k_pool_reload(
    const __bf16* __restrict__ conv_out, const float* __restrict__ ab,
    const float* __restrict__ w2, const float* __restrict__ b2, float* __restrict__ out) {
    __shared__ float red[64][65];
    __shared__ float pooled[64], red2[2][64];
    int img = blockIdx.x, t = threadIdx.x;
    int pidx = t >> 3, ocg = t & 7;
    float a[8], bb[8];
#pragma unroll
    for (int j = 0; j < 8; ++j) {
        a[j]  = ab[(ocg * 8 + j) * 2];
        bb[j] = ab[(ocg * 8 + j) * 2 + 1];
    }
    float s[8];
#pragma unroll
    for (int j = 0; j < 8; ++j) s[j] = 0.f;
    const __bf16* src = conv_out + (size_t)img * Pp * 64 + ocg * 8;
    for (int p = pidx; p < Pp; p += 64) {
        short8 v = *(const short8*)(src + (size_t)p * 64);
#pragma unroll
        for (int j = 0; j < 8; ++j)
            s[j] += fmaxf(fmaf(a[j], tof(v[j]), bb[j]), 0.f);
    }
#pragma unroll
    for (int j = 0; j < 8; ++j) red[pidx][ocg * 8 + j] = s[j];
    __syncthreads();
    if (t < 64) {
        float S = 0.f;
        for (int p = 0; p < 64; ++p) S += red[p][t];
        pooled[t] = S * (1.f / (float)Pp);
    }
    __syncthreads();
    if (t < 128) {
        int j = t >> 6, c = t & 63;
        red2[j][c] = pooled[c] * w2[j * 64 + c];
    }
    __syncthreads();
    if (t < 2) {
        float ss = b2[t];
        for (int c = 0; c < 64; ++c) ss += red2[t][c];
        out[img * 2 + t] = ss;
    }
}

// ============ host ============
extern "C" void kernel_launch(void* const* d_in, const int* in_sizes, int n_in,
                              void* d_out, int out_size, void* d_ws, size_t ws_size,
                              hipStream_t stream) {
    const float* q   = (const float*)d_in[0];
    const float* hm  = (const float*)d_in[1];
    const float* w1  = (const float*)d_in[2];
    const float* b1  = (const float*)d_in[3];
    const float* w2  = (const float*)d_in[4];
    const float* b2  = (const float*)d_in[5];
    const float* w3  = (const float*)d_in[6];
    const float* b3  = (const float*)d_in[7];
    const float* cw  = (const float*)d_in[8];
    const float* cb  = (const float*)d_in[9];
    const float* gam = (const float*)d_in[10];
    const float* bet = (const float*)d_in[11];
    const float* c2w = (const float*)d_in[12];
    const float* c2b = (const float*)d_in[13];
    float* out = (float*)d_out;
    char* ws = (char*)d_ws;

    float* theta = (float*)(ws + OFF_THETA);
    __bf16* wb   = (__bf16*)(ws + OFF_WB);
    float* ab    = (float*)(ws + OFF_AB);

    bool hmt = ws_size >= NEED_HMT;
    __bf16* hmT      = (__bf16*)(ws + OFF_HMT);
    float* partials  = (float*)(ws + (hmt ? OFF_PART_H : OFF_PART_L));
    __bf16* conv_out = (__bf16*)(ws + (hmt ? OFF_CONV_H : OFF_CONV_L));

    k_theta<<<NIMG, 64, 0, stream>>>(q, w1, b1, w2, b2, w3, b3, theta);
    k_wcvt2<<<(64 * KP + 255) / 256, 256, 0, stream>>>(cw, wb);
    if (hmt) {
        k_hmT<<<Bc * HW, 192, 0, stream>>>(hm, hmT);
        k_conv2<1><<<NBLK2, 512, 0, stream>>>(hm, hmT, theta, wb, cb, partials, conv_out);
    } else {
        k_conv2<0><<<NBLK2, 512, 0, stream>>>(hm, hmT, theta, wb, cb, partials, conv_out);
    }
    k_stats<<<64, 256, 0, stream>>>(partials, gam, bet, ab);
    k_pool_reload<<<NIMG, 512, 0, stream>>>(conv_out, ab, c2w, c2b, out);
}

// Round 8
// 151.109 us; speedup vs baseline: 17.4491x; 1.3994x over previous
//
#include <hip/hip_runtime.h>

// ---------------- problem constants ----------------
constexpr int Bc = 2, Nc = 256, CHM = 62;
constexpr int HW = 180;            // heatmap H=W
constexpr int OH = 38;             // conv out H=W
constexpr int Pp = OH * OH;        // 1444 positions
constexpr int NIMG = Bc * Nc;      // 512 images (n-major: img = n*B + b)
constexpr int R2 = 8;              // output rows per conv block
constexpr int NRB2 = 5;            // row-blocks per image (8,8,8,8,6)
constexpr int NBLK2 = NIMG * NRB2; // 2560
constexpr int KP = 576;            // padded K = 9 taps * 64 ch

// ---------------- ws layout (bytes) ----------------
constexpr size_t OFF_THETA = 0;            // 512*6*4        = 12,288
constexpr size_t OFF_WB    = 16384;        // 64*576*2 bf16  = 73,728
constexpr size_t OFF_AB    = 90112;        // 64*2*4         = 512
// hmT path:
constexpr size_t OFF_HMT    = 131072;      // 2*180*180*64*2 = 8,294,400 -> 8,425,472
constexpr size_t OFF_PART_H = 8425472;     // 2560*64*2*4    = 1,310,720 -> 9,736,192
constexpr size_t OFF_CONV_H = 9736192;     // + 94,633,984   -> 104,370,176
constexpr size_t NEED_HMT   = 104370176;   // proven available (rounds 4/5/6 ran this path)
// legacy path (no hmT):
constexpr size_t OFF_PART_L = 131072;
constexpr size_t OFF_CONV_L = 1441792;     // + 94,633,984 -> 96,075,776

typedef __attribute__((ext_vector_type(8))) short  short8;
typedef __attribute__((ext_vector_type(8))) __bf16 bf16x8;
typedef __attribute__((ext_vector_type(4))) float  f32x4;

__device__ __forceinline__ bf16x8 bc(short8 v) { return __builtin_bit_cast(bf16x8, v); }
__device__ __forceinline__ float tof(short s) {
    return __uint_as_float(((unsigned)(unsigned short)s) << 16);
}

// ============ K1: fc_loc MLP -> theta[img][6], img = n*B + b ============
__global__ void k_theta(const float* __restrict__ q,
                        const float* __restrict__ w1, const float* __restrict__ b1,
                        const float* __restrict__ w2, const float* __restrict__ b2,
                        const float* __restrict__ w3, const float* __restrict__ b3,
                        float* __restrict__ theta) {
    __shared__ float qv[256], h1[64], h2[64];
    int qi = blockIdx.x;           // = b*N + n
    int t  = threadIdx.x;          // 64 threads
    int b = qi >> 8, n = qi & 255;
    const float* qrow = q + qi * 256;
    for (int i = t; i < 256; i += 64) qv[i] = qrow[i];
    __syncthreads();
    float s = b1[t];
    const float* wr = w1 + t * 256;
    for (int i = 0; i < 256; ++i) s = fmaf(qv[i], wr[i], s);
    h1[t] = fmaxf(s, 0.f);
    __syncthreads();
    s = b2[t]; wr = w2 + t * 64;
    for (int i = 0; i < 64; ++i) s = fmaf(h1[i], wr[i], s);
    h2[t] = fmaxf(s, 0.f);
    __syncthreads();
    if (t < 6) {
        s = b3[t]; wr = w3 + t * 64;
        for (int i = 0; i < 64; ++i) s = fmaf(h2[i], wr[i], s);
        theta[(n * Bc + b) * 6 + t] = s;
    }
}

// ============ K2: conv1 weights fp32 [oc][ic][ky][kx] -> bf16 wb[n][k], k=(tap*64+ic) ============
__global__ void k_wcvt2(const float* __restrict__ w, __bf16* __restrict__ wb) {
    int idx = blockIdx.x * 256 + threadIdx.x;      // over 64*576
    if (idx < 64 * KP) {
        int n = idx / KP, k = idx - n * KP;
        int tap = k >> 6, ic = k & 63;
        float v = (ic < CHM) ? w[(n * CHM + ic) * 9 + tap] : 0.f;
        wb[idx] = (__bf16)v;
    }
}

// ============ K2b: heatmap [2][62][180][180] f32 -> hmT [2][180*180][64] bf16 ============
__global__ __launch_bounds__(192) void k_hmT(const float* __restrict__ hm, __bf16* __restrict__ hmT) {
    int by = blockIdx.x;           // b*180 + y
    int b = by / HW, y = by - b * HW;
    int x = threadIdx.x;
    if (x < HW) {
        const float* src = hm + (size_t)b * CHM * (HW * HW) + y * HW + x;
        __bf16* dst = hmT + ((size_t)(b * (HW * HW) + y * HW + x)) * 64;
#pragma unroll
        for (int g = 0; g < 8; ++g) {
            bf16x8 v;
#pragma unroll
            for (int j = 0; j < 8; ++j) {
                int c = g * 8 + j;
                v[j] = (c < CHM) ? (__bf16)src[(size_t)c * (HW * HW)] : (__bf16)0.f;
            }
            *(bf16x8*)(dst + g * 8) = v;
        }
    }
}

// ============ K3: fused sample + MFMA implicit-GEMM conv ============
// 512 threads = 8 waves = 4 oc-tiles (h) x 2 m-pair-parity (qp).
// strip LDS: [rx<=10*40][ic:64] bf16, 16B-granular swizzle: elem ^= (x&7)<<3
// sampling (HMT): task = (position, ch-group); 8 consecutive lanes share one
// 128B corner vector -> ~16 lines per wave-load instead of 64 (TA relief).
// NOTE: macro internals underscore-prefixed — round-7 failure was `int p=(p)`
// self-shadowing when called as PREP(T, p, ...).
#define PREP(S, PIDX, VLD) \
    int o00##S, o10##S, o01##S, o11##S, eb##S, sw##S; \
    float w00##S, w10##S, w01##S, w11##S; \
    { int _p = (PIDX); \
      int _r = _p / 40, _x = _p - _r * 40; \
      float _gx = (2 * _x + 1) * 0.025f - 1.f; \
      float _gy = (2 * (oy0 + _r) + 1) * 0.025f - 1.f; \
      float _X = fmaf(t00, _gx, fmaf(t01, _gy, t02)); \
      float _Y = fmaf(t10, _gx, fmaf(t11, _gy, t12)); \
      float _ix = fmaf(_X, 90.f, 89.5f), _iy = fmaf(_Y, 90.f, 89.5f); \
      float _xf = floorf(_ix), _yf = floorf(_iy); \
      float _fx = _ix - _xf, _fy = _iy - _yf; \
      int _x0 = (int)_xf, _y0 = (int)_yf; \
      bool _xi0 = (unsigned)_x0 < (unsigned)HW, _xi1 = (unsigned)(_x0 + 1) < (unsigned)HW; \
      bool _yi0 = (unsigned)_y0 < (unsigned)HW, _yi1 = (unsigned)(_y0 + 1) < (unsigned)HW; \
      float _vm = (VLD) ? 1.f : 0.f; \
      w00##S = (_xi0 & _yi0) ? (1.f - _fx) * (1.f - _fy) * _vm : 0.f; \
      w10##S = (_xi1 & _yi0) ? _fx * (1.f - _fy) * _vm : 0.f; \
      w01##S = (_xi0 & _yi1) ? (1.f - _fx) * _fy * _vm : 0.f; \
      w11##S = (_xi1 & _yi1) ? _fx * _fy * _vm : 0.f; \
      o00##S = (_xi0 & _yi0) ? _y0 * HW + _x0 : 0; \
      o10##S = (_xi1 & _yi0) ? _y0 * HW + _x0 + 1 : 0; \
      o01##S = (_xi0 & _yi1) ? (_y0 + 1) * HW + _x0 : 0; \
      o11##S = (_xi1 & _yi1) ? (_y0 + 1) * HW + _x0 + 1 : 0; \
      eb##S = _p << 6; sw##S = (_x & 7) << 3; \
    }

template<int HMT>
__global__ __launch_bounds__(512, 4) void k_conv2(
    const float* __restrict__ heatmap, const __bf16* __restrict__ hmT,
    const float* __restrict__ theta, const __bf16* __restrict__ wb,
    const float* __restrict__ bias, float* __restrict__ partials,
    __bf16* __restrict__ conv_out) {
    __shared__ char smem[52224];                 // 10*40*64*2 strip + 1KB red

    int bid = blockIdx.x;
    int n = bid & 255, bsel = (bid >> 8) & 1, ry = bid >> 9;
    int img = n * Bc + bsel;
    int oy0 = ry * R2;
    int nr  = (ry == NRB2 - 1) ? 6 : 8;          // output rows this block
    int t = threadIdx.x;
    int lane = t & 63, wv = t >> 6;
    int col = lane & 15, chunk = lane >> 4;
    int h = wv & 3, qp = wv >> 2;                // oc-tile, m-pair parity

    // ---- B fragments straight from global into registers (n-tile = h) ----
    short8 bfr[18];
    {
        int nn = h * 16 + col;
        const char* wp = (const char*)wb + (size_t)nn * (KP * 2) + chunk * 16;
#pragma unroll
        for (int s = 0; s < 18; ++s)
            bfr[s] = *(const short8*)(wp + s * 64);
    }

    // ---- sampling ----
    const float* th = theta + img * 6;
    float t00 = th[0], t01 = th[1], t02 = th[2];
    float t10 = th[3], t11 = th[4], t12 = th[5];
    int rows = nr + 2, npos = rows * 40;

    if constexpr (HMT) {
        const char* hb = (const char*)(hmT + (size_t)bsel * ((size_t)HW * HW * 64));
        int ntask = npos * 8;                    // (position, ch-group) tasks
        for (int v = t; v < ntask; v += 512) {
            int p = v >> 3, cg = v & 7;
            PREP(T, p, true)
            int co = cg * 16;                    // byte offset of ch-group
            short8 a00 = *(const short8*)(hb + (size_t)o00T * 128 + co);
            short8 a10 = *(const short8*)(hb + (size_t)o10T * 128 + co);
            short8 a01 = *(const short8*)(hb + (size_t)o01T * 128 + co);
            short8 a11 = *(const short8*)(hb + (size_t)o11T * 128 + co);
            bf16x8 v0;
#pragma unroll
            for (int j = 0; j < 8; ++j) {
                float f = w00T * tof(a00[j]);
                f = fmaf(w10T, tof(a10[j]), f);
                f = fmaf(w01T, tof(a01[j]), f);
                f = fmaf(w11T, tof(a11[j]), f);
                v0[j] = (__bf16)f;
            }
            *(bf16x8*)(smem + 2 * (ebT | ((cg * 8) ^ swT))) = v0;
        }
    } else {
        if (t < npos) {
            PREP(A, t, true)
            char* sb0 = smem + 2 * ebA;
            const float* hmb = heatmap + (size_t)bsel * CHM * HW * HW;
            auto dofetch = [&](int c) -> float {
                const float* pl = hmb + c * (HW * HW);
                return fmaf(w00A, pl[o00A], fmaf(w10A, pl[o10A],
                       fmaf(w01A, pl[o01A], w11A * pl[o11A])));
            };
#pragma unroll
            for (int cg = 0; cg < 8; ++cg) {
                bf16x8 v0;
#pragma unroll
                for (int j = 0; j < 8; ++j) {
                    int c = cg * 8 + j;
                    v0[j] = (c < CHM) ? (__bf16)dofetch(c) : (__bf16)0.f;
                }
                *(bf16x8*)(sb0 + 2 * ((cg * 8) ^ swA)) = v0;
            }
        }
    }
    __syncthreads();

    // ---- MFMA m-loop: wave (h,qp) -> 16 oc, pairs pr=qp,qp+2,.. (2 m-tiles/iter) ----
    float bia = bias[h * 16 + col];
    float ssum = 0.f, ssq = 0.f;
    int mA = col;                                 // A-operand row = lane&15
    int lim = nr * 38 - 1;
    int nt = (nr * 38 + 15) >> 4;                 // 19 or 15
    int npairs = (nt + 1) >> 1;                   // 10 or 8
    __bf16* cobase = conv_out + ((size_t)img * Pp + oy0 * 38) * 64 + (h * 16 + col);
    int cb = chunk << 4;

    for (int pr = qp; pr < npairs; pr += 2) {
        int tt = pr * 2;
        f32x4 acc0 = {0.f, 0.f, 0.f, 0.f}, acc1 = {0.f, 0.f, 0.f, 0.f};
        bool has1 = (tt + 1) < nt;
        int p0 = tt * 16 + mA;       p0 = p0 > lim ? lim : p0;
        int p1 = (tt + 1) * 16 + mA; p1 = p1 > lim ? lim : p1;
        int oyl0 = p0 / 38, ox0 = p0 - oyl0 * 38;
        int oyl1 = p1 / 38, ox1 = p1 - oyl1 * 38;
        int rb0 = oyl0 * 5120, rb1 = oyl1 * 5120;
        int xb0[3], xs0[3], xb1[3], xs1[3];
#pragma unroll
        for (int kk = 0; kk < 3; ++kk) {
            xb0[kk] = (ox0 + kk) * 128; xs0[kk] = ((ox0 + kk) & 7) << 4;
            xb1[kk] = (ox1 + kk) * 128; xs1[kk] = ((ox1 + kk) & 7) << 4;
        }
#pragma unroll
        for (int s = 0; s < 18; ++s) {
            const int tap = s >> 1;
            const int ky = tap / 3, kx = tap % 3;
            const int hb2 = (s & 1) << 6;
            int a0 = rb0 + ky * 5120 + xb0[kx] + ((hb2 | cb) ^ xs0[kx]);
            short8 av0 = *(const short8*)(smem + a0);
            acc0 = __builtin_amdgcn_mfma_f32_16x16x32_bf16(bc(av0), bc(bfr[s]), acc0, 0, 0, 0);
            if (has1) {
                int a1 = rb1 + ky * 5120 + xb1[kx] + ((hb2 | cb) ^ xs1[kx]);
                short8 av1 = *(const short8*)(smem + a1);
                acc1 = __builtin_amdgcn_mfma_f32_16x16x32_bf16(bc(av1), bc(bfr[s]), acc1, 0, 0, 0);
            }
        }
        // epilogue: C row = chunk*4 + reg (position), col = lane&15 (oc)
#pragma unroll
        for (int r2 = 0; r2 < 4; ++r2) {
            int pl = tt * 16 + chunk * 4 + r2;
            if (pl <= lim) {
                float v = acc0[r2] + bia;
                cobase[(size_t)pl * 64] = (__bf16)v;
                ssum += v; ssq = fmaf(v, v, ssq);
            }
        }
        if (has1) {
#pragma unroll
            for (int r2 = 0; r2 < 4; ++r2) {
                int pl = (tt + 1) * 16 + chunk * 4 + r2;
                if (pl <= lim) {
                    float v = acc1[r2] + bia;
                    cobase[(size_t)pl * 64] = (__bf16)v;
                    ssum += v; ssq = fmaf(v, v, ssq);
                }
            }
        }
    }

    // cross-lane: sum lanes {l, l^16, l^32, l^48} (same oc col)
    ssum += __shfl_xor(ssum, 16); ssum += __shfl_xor(ssum, 32);
    ssq  += __shfl_xor(ssq, 16);  ssq  += __shfl_xor(ssq, 32);

    // combine the two qp-waves via LDS red region [2][64][2] @ 51200
    float* redq = (float*)(smem + 51200);
    if (lane < 16) {
        int o = (qp * 64 + h * 16 + lane) * 2;
        redq[o] = ssum; redq[o + 1] = ssq;
    }
    __syncthreads();
    if (t < 64) {
        float S  = redq[t * 2]     + redq[(64 + t) * 2];
        float S2 = redq[t * 2 + 1] + redq[(64 + t) * 2 + 1];
        partials[((size_t)bid * 64 + t) * 2]     = S;
        partials[((size_t)bid * 64 + t) * 2 + 1] = S2;
    }
}

// ============ K3b: reduce per-block sums -> BN a,b per channel ============
__global__ void k_stats(const float* __restrict__ partials, const float* __restrict__ gamma,
                        const float* __restrict__ beta, float* __restrict__ ab) {
    __shared__ float red[256][2];
    int oc = blockIdx.x, t = threadIdx.x;
    float S = 0.f, S2 = 0.f;
    for (int j = t; j < NBLK2; j += 256) {
        S  += partials[((size_t)j * 64 + oc) * 2];
        S2 += partials[((size_t)j * 64 + oc) * 2 + 1];
    }
    red[t][0] = S; red[t][1] = S2;
    __syncthreads();
    for (int off = 128; off >= 1; off >>= 1) {
        if (t < off) { red[t][0] += red[t + off][0]; red[t][1] += red[t + off][1]; }
        __syncthreads();
    }
    if (t == 0) {
        float cnt = (float)NIMG * (float)Pp;
        float mu  = red[0][0] / cnt;
        float var = red[0][1] / cnt - mu * mu;
        float a = gamma[oc] * rsqrtf(var + 1e-5f);
        ab[oc * 2] = a;
        ab[oc * 2 + 1] = beta[oc] - mu * a;
    }
}

// ============ K4: BN+ReLU+pool from conv_out + final 1x1 (vectorized) ============
__global__ __launch_bounds__(512) void k_pool_reload(
    const __bf16* __restrict__ conv_out, const float* __restrict__ ab,
    const float* __restrict__ w2, const float* __restrict__ b2, float* __restrict__ out) {
    __shared__ float red[64][65];
    __shared__ float pooled[64], red2[2][64];
    int img = blockIdx.x, t = threadIdx.x;
    int pidx = t >> 3, ocg = t & 7;
    float a[8], bb[8];
#pragma unroll
    for (int j = 0; j < 8; ++j) {
        a[j]  = ab[(ocg * 8 + j) * 2];
        bb[j] = ab[(ocg * 8 + j) * 2 + 1];
    }
    float s[8];
#pragma unroll
    for (int j = 0; j < 8; ++j) s[j] = 0.f;
    const __bf16* src = conv_out + (size_t)img * Pp * 64 + ocg * 8;
    for (int p = pidx; p < Pp; p += 64) {
        short8 v = *(const short8*)(src + (size_t)p * 64);
#pragma unroll
        for (int j = 0; j < 8; ++j)
            s[j] += fmaxf(fmaf(a[j], tof(v[j]), bb[j]), 0.f);
    }
#pragma unroll
    for (int j = 0; j < 8; ++j) red[pidx][ocg * 8 + j] = s[j];
    __syncthreads();
    if (t < 64) {
        float S = 0.f;
        for (int p = 0; p < 64; ++p) S += red[p][t];
        pooled[t] = S * (1.f / (float)Pp);
    }
    __syncthreads();
    if (t < 128) {
        int j = t >> 6, c = t & 63;
        red2[j][c] = pooled[c] * w2[j * 64 + c];
    }
    __syncthreads();
    if (t < 2) {
        float ss = b2[t];
        for (int c = 0; c < 64; ++c) ss += red2[t][c];
        out[img * 2 + t] = ss;
    }
}

// ============ host ============
extern "C" void kernel_launch(void* const* d_in, const int* in_sizes, int n_in,
                              void* d_out, int out_size, void* d_ws, size_t ws_size,
                              hipStream_t stream) {
    const float* q   = (const float*)d_in[0];
    const float* hm  = (const float*)d_in[1];
    const float* w1  = (const float*)d_in[2];
    const float* b1  = (const float*)d_in[3];
    const float* w2  = (const float*)d_in[4];
    const float* b2  = (const float*)d_in[5];
    const float* w3  = (const float*)d_in[6];
    const float* b3  = (const float*)d_in[7];
    const float* cw  = (const float*)d_in[8];
    const float* cb  = (const float*)d_in[9];
    const float* gam = (const float*)d_in[10];
    const float* bet = (const float*)d_in[11];
    const float* c2w = (const float*)d_in[12];
    const float* c2b = (const float*)d_in[13];
    float* out = (float*)d_out;
    char* ws = (char*)d_ws;

    float* theta = (float*)(ws + OFF_THETA);
    __bf16* wb   = (__bf16*)(ws + OFF_WB);
    float* ab    = (float*)(ws + OFF_AB);

    bool hmt = ws_size >= NEED_HMT;
    __bf16* hmT      = (__bf16*)(ws + OFF_HMT);
    float* partials  = (float*)(ws + (hmt ? OFF_PART_H : OFF_PART_L));
    __bf16* conv_out = (__bf16*)(ws + (hmt ? OFF_CONV_H : OFF_CONV_L));

    k_theta<<<NIMG, 64, 0, stream>>>(q, w1, b1, w2, b2, w3, b3, theta);
    k_wcvt2<<<(64 * KP + 255) / 256, 256, 0, stream>>>(cw, wb);
    if (hmt) {
        k_hmT<<<Bc * HW, 192, 0, stream>>>(hm, hmT);
        k_conv2<1><<<NBLK2, 512, 0, stream>>>(hm, hmT, theta, wb, cb, partials, conv_out);
    } else {
        k_conv2<0><<<NBLK2, 512, 0, stream>>>(hm, hmT, theta, wb, cb, partials, conv_out);
    }
    k_stats<<<64, 256, 0, stream>>>(partials, gam, bet, ab);
    k_pool_reload<<<NIMG, 512, 0, stream>>>(conv_out, ab, c2w, c2b, out);
}